// Round 6
// baseline (439.869 us; speedup 1.0000x reference)
//
#include <hip/hip_runtime.h>
#include <stdint.h>
#include <math.h>

// Problem constants
#define BN 4096
#define TT 20
#define HH 256
#define EE 128
#define KK 5
#define NCOND 5

// ws layout (float indices)
#define WS_KEYS 0                       // 320 u32: per step, 4 heads x (k1.x,k1.y,k2.x,k2.y)
#define WS_TSC  512                     // 20*1024 cumulative ts@Wk[384:404]
#define WS_WTT  20992                   // 256*80 head weights transposed [q][o], o padded to 80
#define WS_BIAS 41472                   // 80 concat head biases (pad 0)
#define WS_T1   41552                   // 5*128  We1@We2
#define WS_EB2  42192                   // 128    be1@We2 + be2
#define WS_ZC   42320                   // 1024   (be1@We2+be2)@Wk1 + bl
#define WS_M    43344                   // 5*1024 We1@We2@Wk1
#define WS_WSUM 48464                   // 256*1024  Wk[128:384] + Wr
#define WS_END  310608                  // 1.24 MB

#define TINYF 1.17549435e-38f
#define LO_N  0.99999994f               // -nextafter(-1,0)

// ---------------- Threefry-2x32 (JAX-exact) ----------------
__device__ __forceinline__ void tf2(uint32_t k0, uint32_t k1, uint32_t x0, uint32_t x1,
                                    uint32_t& o0, uint32_t& o1) {
  const uint32_t ks2 = k0 ^ k1 ^ 0x1BD11BDAu;
  x0 += k0; x1 += k1;
#define RND(r) { x0 += x1; x1 = (x1 << (r)) | (x1 >> (32 - (r))); x1 ^= x0; }
  RND(13) RND(15) RND(26) RND(6)   x0 += k1;  x1 += ks2 + 1u;
  RND(17) RND(29) RND(16) RND(24)  x0 += ks2; x1 += k0 + 2u;
  RND(13) RND(15) RND(26) RND(6)   x0 += k0;  x1 += k1 + 3u;
  RND(17) RND(29) RND(16) RND(24)  x0 += k1;  x1 += ks2 + 4u;
  RND(13) RND(15) RND(26) RND(6)   x0 += ks2; x1 += k0 + 5u;
#undef RND
  o0 = x0; o1 = x1;
}

// jax_threefry_partitionable: bits[n] = a ^ b, (a,b) = threefry2x32(key, (0, n))
__device__ __forceinline__ uint32_t pbits(uint32_t k0, uint32_t k1, uint32_t n) {
  uint32_t a, b;
  tf2(k0, k1, 0u, n, a, b);
  return a ^ b;
}

__device__ __forceinline__ float u01f(uint32_t bits) {
  return __uint_as_float((bits >> 9) | 0x3f800000u) - 1.0f;
}

// XLA ErfInv32 (Giles polynomial)
__device__ __forceinline__ float erfinv_f(float x) {
  float w = -log1pf(-x * x);
  float p;
  if (w < 5.0f) {
    w = w - 2.5f;
    p = 2.81022636e-08f;
    p = 3.43273939e-07f + p * w;
    p = -3.5233877e-06f + p * w;
    p = -4.39150654e-06f + p * w;
    p = 0.00021858087f  + p * w;
    p = -0.00125372503f + p * w;
    p = -0.00417768164f + p * w;
    p = 0.246640727f    + p * w;
    p = 1.50140941f     + p * w;
  } else {
    w = sqrtf(w) - 3.0f;
    p = -0.000200214257f;
    p = 0.000100950558f + p * w;
    p = 0.00134934322f  + p * w;
    p = -0.00367342844f + p * w;
    p = 0.00573950773f  + p * w;
    p = -0.0076224613f  + p * w;
    p = 0.00943887047f  + p * w;
    p = 1.00167406f     + p * w;
    p = 2.83297682f     + p * w;
  }
  return p * x;
}

// XLA lowers logistic as 0.5 + 0.5*tanh(0.5x)
__device__ __forceinline__ float sigf(float x) { return 0.5f + 0.5f * tanhf(0.5f * x); }

// round-to-nearest-even f32 -> bf16 bits
__device__ __forceinline__ uint32_t bf16rne(float f) {
  uint32_t u = __float_as_uint(f);
  return (u + 0x7fffu + ((u >> 16) & 1u)) >> 16;
}

// ---------------- prep_a: keys, tsc, WTT/bias, T1/eb2, WSUM ----------------
__global__ __launch_bounds__(256) void prep_a(
    const float* __restrict__ Wk, const float* __restrict__ Wr,
    const float* __restrict__ We1, const float* __restrict__ be1,
    const float* __restrict__ We2, const float* __restrict__ be2,
    const float* __restrict__ Wm, const float* __restrict__ bm,
    const float* __restrict__ Wy, const float* __restrict__ by,
    const float* __restrict__ Wf, const float* __restrict__ bf,
    const float* __restrict__ Wfa, const float* __restrict__ bfa,
    float* __restrict__ ws) {
  const int bid = blockIdx.x, tid = threadIdx.x;
  if (bid == 0) {
    if (tid < 4) {
      uint32_t* keys = (uint32_t*)ws;
      const int l = tid;                 // 0=km 1=ky 2=kf 3=kfa
      uint32_t kx = 0u, ky = 42u;        // jax.random.key(42)
      for (int t = 0; t < TT; ++t) {
        uint32_t hx, hy;
        tf2(kx, ky, 0u, (uint32_t)(l + 1), hx, hy);
        uint32_t k1x, k1y, k2x, k2y;
        tf2(hx, hy, 0u, 0u, k1x, k1y);
        tf2(hx, hy, 0u, 1u, k2x, k2y);
        keys[t * 16 + l * 4 + 0] = k1x;
        keys[t * 16 + l * 4 + 1] = k1y;
        keys[t * 16 + l * 4 + 2] = k2x;
        keys[t * 16 + l * 4 + 3] = k2y;
        uint32_t nx, ny;
        tf2(kx, ky, 0u, 0u, nx, ny);
        kx = nx; ky = ny;
      }
    }
  } else if (bid <= 4) {
    const int col = (bid - 1) * 256 + tid;
    float s = 0.0f;
    for (int p = 0; p < TT; ++p) {
      s += Wk[(size_t)(EE + HH + p) * 1024 + col];
      ws[WS_TSC + p * 1024 + col] = s;
    }
  } else if (bid <= 84) {
    // WTT[q][o] transposed head weights, o-padded to 80
    const int idx = (bid - 5) * 256 + tid;   // < 20480
    const int q = idx / 80, o = idx - q * 80;
    float v = 0.0f;
    if (o < 30)      v = Wm[q * 30 + o];
    else if (o < 45) v = Wy[q * 15 + (o - 30)];
    else if (o < 60) v = Wf[q * 15 + (o - 45)];
    else if (o < 75) v = Wfa[q * 15 + (o - 60)];
    ws[WS_WTT + idx] = v;
  } else if (bid == 85) {
    if (tid < 80) {
      float v = 0.0f;
      if (tid < 30)      v = bm[tid];
      else if (tid < 45) v = by[tid - 30];
      else if (tid < 60) v = bf[tid - 45];
      else if (tid < 75) v = bfa[tid - 60];
      ws[WS_BIAS + tid] = v;
    }
  } else if (bid == 86) {
    // T1[c][q] = sum_e We1[c][e]*We2[e][q]; eb2[q] = be2[q] + sum_e be1[e]*We2[e][q]
    if (tid < EE) {
      const int q = tid;
      float t0 = 0.f, t1 = 0.f, t2 = 0.f, t3 = 0.f, t4 = 0.f;
      float eb = be2[q];
      for (int e = 0; e < EE; ++e) {
        const float w2 = We2[e * EE + q];
        t0 = fmaf(We1[0 * EE + e], w2, t0);
        t1 = fmaf(We1[1 * EE + e], w2, t1);
        t2 = fmaf(We1[2 * EE + e], w2, t2);
        t3 = fmaf(We1[3 * EE + e], w2, t3);
        t4 = fmaf(We1[4 * EE + e], w2, t4);
        eb = fmaf(be1[e], w2, eb);
      }
      ws[WS_T1 + 0 * EE + q] = t0;
      ws[WS_T1 + 1 * EE + q] = t1;
      ws[WS_T1 + 2 * EE + q] = t2;
      ws[WS_T1 + 3 * EE + q] = t3;
      ws[WS_T1 + 4 * EE + q] = t4;
      ws[WS_EB2 + q] = eb;
    }
  } else {
    // WSUM[q][col] = Wk[128+q][col] + Wr[q][col]
    const int idx = (bid - 87) * 256 + tid;
    if (idx < 256 * 1024) {
      const int q = idx >> 10, col = idx & 1023;
      ws[WS_WSUM + idx] = Wk[(size_t)(EE + q) * 1024 + col] + Wr[(size_t)q * 1024 + col];
    }
  }
}

// ---------------- prep_b: M = T1@Wk1 (5x1024), zc = eb2@Wk1 + bl ----------------
__global__ __launch_bounds__(256) void prep_b(
    const float* __restrict__ Wk, const float* __restrict__ bl,
    float* __restrict__ ws) {
  const int col = blockIdx.x * 256 + threadIdx.x;   // 0..1023
  float m0 = 0.f, m1 = 0.f, m2 = 0.f, m3 = 0.f, m4 = 0.f;
  float zacc = bl[col];
  for (int q = 0; q < EE; ++q) {
    const float wv = Wk[(size_t)q * 1024 + col];
    m0 = fmaf(ws[WS_T1 + 0 * EE + q], wv, m0);
    m1 = fmaf(ws[WS_T1 + 1 * EE + q], wv, m1);
    m2 = fmaf(ws[WS_T1 + 2 * EE + q], wv, m2);
    m3 = fmaf(ws[WS_T1 + 3 * EE + q], wv, m3);
    m4 = fmaf(ws[WS_T1 + 4 * EE + q], wv, m4);
    zacc = fmaf(ws[WS_EB2 + q], wv, zacc);
  }
  ws[WS_M + 0 * 1024 + col] = m0;
  ws[WS_M + 1 * 1024 + col] = m1;
  ws[WS_M + 2 * 1024 + col] = m2;
  ws[WS_M + 3 * 1024 + col] = m3;
  ws[WS_M + 4 * 1024 + col] = m4;
  ws[WS_ZC + col] = zacc;
}

// ---------------- main: 8 rows/block, 512 blocks (2 blocks/CU), 20 steps ----------------
// Roles: Phase A: thread (u = tid&255, half = tid>>8) -> 4 rows x unit u.
//        Phase B: thread (ch = tid>>7, oo = tid&127, active oo<75): head output oo,
//                 q-chunk ch*64..+64 with weights bf16-packed in 32 VGPRs (persistent).
//        Phase C: tid<256: lane = (row r, head, k) with 8-lane shfl groups.
__global__ __launch_bounds__(512, 4) void decode_main(
    const float* __restrict__ conditions, const float* __restrict__ state_h,
    const float* __restrict__ state_c, const float* __restrict__ ws,
    float* __restrict__ out) {
  __shared__ float Msh[5 * 1024];       // 20 KB
  __shared__ float hsh[8 * HH];         // 8 KB: state_h staging -> h
  __shared__ float pp[4][8][80];        // 10 KB head partials per chunk
  __shared__ float psh[8 * 80];         // 2.5 KB head outputs
  __shared__ float biasL[80];
  __shared__ float conds[8 * 8];
  __shared__ uint32_t keysL[TT * 16];

  const int tid = threadIdx.x;
  const int row0 = blockIdx.x * 8;
  const int u = tid & 255;
  const int half = tid >> 8;
  const int rbase = half * 4;

  // ---- prologue staging ----
  for (int i = tid; i < 5 * 1024; i += 512) Msh[i] = ws[WS_M + i];
  if (tid < 80) biasL[tid] = ws[WS_BIAS + tid];
  for (int i = tid; i < TT * 16; i += 512) keysL[i] = ((const uint32_t*)ws)[WS_KEYS + i];
  if (tid < 8 * NCOND) {
    const int r = tid / NCOND, c = tid - r * NCOND;
    conds[r * 8 + c] = conditions[(size_t)(row0 + r) * (TT * NCOND) + c];  // [:,0,:]
  }
  for (int i = tid; i < 8 * HH; i += 512) hsh[i] = state_h[(size_t)row0 * HH + i];

  // persistent bf16-packed head weights (chunk ch, output oo)
  const int ch = tid >> 7;
  const int oo = tid & 127;
  const bool bact = (oo < 75);
  uint32_t wp[32];
  if (bact) {
#pragma unroll
    for (int j2 = 0; j2 < 32; ++j2) {
      const float f0 = ws[WS_WTT + (ch * 64 + 2 * j2 + 0) * 80 + oo];
      const float f1 = ws[WS_WTT + (ch * 64 + 2 * j2 + 1) * 80 + oo];
      wp[j2] = bf16rne(f0) | (bf16rne(f1) << 16);
    }
  }

  float sc[4];
#pragma unroll
  for (int rr = 0; rr < 4; ++rr) sc[rr] = state_c[(size_t)(row0 + rbase + rr) * HH + u];
  __syncthreads();

  // ---- step-invariant cz[gate][row] = zc + state_h @ WSUM ----
  float cz[4][4];
#pragma unroll
  for (int g = 0; g < 4; ++g) {
    const float z = ws[WS_ZC + g * 256 + u];
#pragma unroll
    for (int rr = 0; rr < 4; ++rr) cz[g][rr] = z;
  }
  for (int q = 0; q < HH; ++q) {
    const float w0 = ws[WS_WSUM + q * 1024 + u];
    const float w1 = ws[WS_WSUM + q * 1024 + 256 + u];
    const float w2 = ws[WS_WSUM + q * 1024 + 512 + u];
    const float w3 = ws[WS_WSUM + q * 1024 + 768 + u];
#pragma unroll
    for (int rr = 0; rr < 4; ++rr) {
      const float e = hsh[(rbase + rr) * HH + q];
      cz[0][rr] = fmaf(e, w0, cz[0][rr]);
      cz[1][rr] = fmaf(e, w1, cz[1][rr]);
      cz[2][rr] = fmaf(e, w2, cz[2][rr]);
      cz[3][rr] = fmaf(e, w3, cz[3][rr]);
    }
  }
  __syncthreads();   // hsh(state_h) dead -> h buffer

  for (int t = 0; t < TT; ++t) {
    // ---- Phase A: z = cond@M + cz + tsc[t]; gates -> h -> hsh ----
    {
      const float ts0 = ws[WS_TSC + t * 1024 + u];
      const float ts1 = ws[WS_TSC + t * 1024 + 256 + u];
      const float ts2 = ws[WS_TSC + t * 1024 + 512 + u];
      const float ts3 = ws[WS_TSC + t * 1024 + 768 + u];
      float mA[5], mB[5], mC[5], mD[5];
#pragma unroll
      for (int c = 0; c < 5; ++c) {
        mA[c] = Msh[c * 1024 + u];
        mB[c] = Msh[c * 1024 + 256 + u];
        mC[c] = Msh[c * 1024 + 512 + u];
        mD[c] = Msh[c * 1024 + 768 + u];
      }
#pragma unroll
      for (int rr = 0; rr < 4; ++rr) {
        const int row = rbase + rr;
        const float c0 = conds[row * 8 + 0], c1 = conds[row * 8 + 1], c2 = conds[row * 8 + 2],
                    c3 = conds[row * 8 + 3], c4 = conds[row * 8 + 4];
        float zi = cz[0][rr] + ts0, zf = cz[1][rr] + ts1,
              zg = cz[2][rr] + ts2, zo = cz[3][rr] + ts3;
        zi = fmaf(c0, mA[0], zi); zi = fmaf(c1, mA[1], zi); zi = fmaf(c2, mA[2], zi);
        zi = fmaf(c3, mA[3], zi); zi = fmaf(c4, mA[4], zi);
        zf = fmaf(c0, mB[0], zf); zf = fmaf(c1, mB[1], zf); zf = fmaf(c2, mB[2], zf);
        zf = fmaf(c3, mB[3], zf); zf = fmaf(c4, mB[4], zf);
        zg = fmaf(c0, mC[0], zg); zg = fmaf(c1, mC[1], zg); zg = fmaf(c2, mC[2], zg);
        zg = fmaf(c3, mC[3], zg); zg = fmaf(c4, mC[4], zg);
        zo = fmaf(c0, mD[0], zo); zo = fmaf(c1, mD[1], zo); zo = fmaf(c2, mD[2], zo);
        zo = fmaf(c3, mD[3], zo); zo = fmaf(c4, mD[4], zo);
        const float cv = sigf(zf) * sc[rr] + sigf(zi) * tanhf(zg);
        const float hv = sigf(zo) * tanhf(cv);
        hsh[row * HH + u] = hv;
      }
    }
    __syncthreads();
    // ---- Phase B: partial head dots from register weights ----
    if (bact) {
      float p[8];
#pragma unroll
      for (int r = 0; r < 8; ++r) p[r] = 0.0f;
      const float4* hsh4 = (const float4*)hsh;
#pragma unroll
      for (int j4 = 0; j4 < 16; ++j4) {
        const uint32_t pa = wp[2 * j4], pb = wp[2 * j4 + 1];
        const float w0 = __uint_as_float(pa << 16);
        const float w1 = __uint_as_float(pa & 0xffff0000u);
        const float w2 = __uint_as_float(pb << 16);
        const float w3 = __uint_as_float(pb & 0xffff0000u);
#pragma unroll
        for (int r = 0; r < 8; ++r) {
          const float4 hv = hsh4[r * 64 + ch * 16 + j4];
          p[r] = fmaf(hv.x, w0, p[r]);
          p[r] = fmaf(hv.y, w1, p[r]);
          p[r] = fmaf(hv.z, w2, p[r]);
          p[r] = fmaf(hv.w, w3, p[r]);
        }
      }
#pragma unroll
      for (int r = 0; r < 8; ++r) pp[ch][r][oo] = p[r];
    }
    __syncthreads();
    // ---- reduce partials: psh[r][o] = bias + sum_ch pp ----
    for (int s = tid; s < 640; s += 512) {
      const int rr = s / 80, o = s - rr * 80;
      if (o < 75) {
        float acc = biasL[o] + pp[0][rr][o];
        acc += pp[1][rr][o];
        acc += pp[2][rr][o];
        acc += pp[3][rr][o];
        psh[rr * 80 + o] = acc;
      }
    }
    __syncthreads();
    // ---- Phase C: wave-parallel sampling; lane = (r, head, k) ----
    if (tid < 256) {
      const int g8 = tid >> 3, k = tid & 7;
      const int r = g8 >> 2, head = g8 & 3;
      const int row = row0 + r;
      const int base = head ? (30 + 15 * (head - 1)) : 0;
      const uint32_t g0 = keysL[t * 16 + head * 4 + 0], g1 = keysL[t * 16 + head * 4 + 1];
      const uint32_t n0 = keysL[t * 16 + head * 4 + 2], n1 = keysL[t * 16 + head * 4 + 3];
      const float lk = (k < 5) ? psh[r * 80 + base + k] : -INFINITY;
      float mx = fmaxf(lk, __shfl_xor(lk, 1));
      mx = fmaxf(mx, __shfl_xor(mx, 2));
      mx = fmaxf(mx, __shfl_xor(mx, 4));
      const float ek = (k < 5) ? expf(lk - mx) : 0.0f;
      float ss = ek + __shfl_xor(ek, 1);
      ss += __shfl_xor(ss, 2);
      ss += __shfl_xor(ss, 4);
      // gumbel argmax, first-max-wins
      float v = -INFINITY;
      if (k < 5) {
        float uv = u01f(pbits(g0, g1, (uint32_t)(row * 5 + k)));
        uv = fmaxf(TINYF, uv * (1.0f - TINYF) + TINYF);
        v = lk - logf(-logf(uv));
      }
      float vm = fmaxf(v, __shfl_xor(v, 1));
      vm = fmaxf(vm, __shfl_xor(vm, 2));
      vm = fmaxf(vm, __shfl_xor(vm, 4));
      int cand = (v == vm) ? k : 8;
      cand = min(cand, __shfl_xor(cand, 1));
      cand = min(cand, __shfl_xor(cand, 2));
      cand = min(cand, __shfl_xor(cand, 4));
      const int idx = cand;
      const size_t ob = head
          ? ((size_t)BN * TT * 30 + (size_t)(head - 1) * BN * TT * 15 + ((size_t)row * TT + t) * 15)
          : ((size_t)row * TT + t) * 30;
      if (k < 5) {
        out[ob + k] = ek / ss;
        out[ob + 5 + k] = psh[r * 80 + base + 5 + k];
        out[ob + 10 + k] = expf(psh[r * 80 + base + 10 + k]);
        if (head == 0) {
          out[ob + 15 + k] = psh[r * 80 + 15 + k];
          out[ob + 20 + k] = expf(psh[r * 80 + 20 + k]);
          out[ob + 25 + k] = tanhf(psh[r * 80 + 25 + k]);
        }
      }
      if (k == 0) {
        if (head == 0) {
          float uz0 = u01f(pbits(n0, n1, (uint32_t)(row * 2 + 0))) * 2.0f - LO_N;
          float uz1 = u01f(pbits(n0, n1, (uint32_t)(row * 2 + 1))) * 2.0f - LO_N;
          uz0 = fmaxf(-LO_N, uz0); uz1 = fmaxf(-LO_N, uz1);
          const float z0 = 1.41421356f * erfinv_f(uz0);
          const float z1 = 1.41421356f * erfinv_f(uz1);
          const float mu = psh[r * 80 + 5 + idx];
          const float sl = expf(psh[r * 80 + 10 + idx]);
          const float mula = psh[r * 80 + 15 + idx];
          const float sla = expf(psh[r * 80 + 20 + idx]);
          const float rho = tanhf(psh[r * 80 + 25 + idx]);
          conds[r * 8 + 0] = mu + sl * z0;
          conds[r * 8 + 1] = mula + sla * (rho * z0 + sqrtf(1.0f - rho * rho) * z1);
        } else {
          float uz = u01f(pbits(n0, n1, (uint32_t)row)) * 2.0f - LO_N;
          uz = fmaxf(-LO_N, uz);
          const float zz = 1.41421356f * erfinv_f(uz);
          conds[r * 8 + 1 + head] =
              psh[r * 80 + base + 5 + idx] + expf(psh[r * 80 + base + 10 + idx]) * zz;
        }
      }
    }
    __syncthreads();
  }
}

extern "C" void kernel_launch(void* const* d_in, const int* in_sizes, int n_in,
                              void* d_out, int out_size, void* d_ws, size_t ws_size,
                              hipStream_t stream) {
  const float* conditions = (const float*)d_in[0];
  const float* state_h = (const float*)d_in[1];
  const float* state_c = (const float*)d_in[2];
  // d_in[3] = steps_n (=20, compile-time TT)
  const float* We1 = (const float*)d_in[4];
  const float* be1 = (const float*)d_in[5];
  const float* We2 = (const float*)d_in[6];
  const float* be2 = (const float*)d_in[7];
  const float* Wk  = (const float*)d_in[8];
  const float* Wr  = (const float*)d_in[9];
  const float* bl  = (const float*)d_in[10];
  const float* Wm  = (const float*)d_in[11];
  const float* bm  = (const float*)d_in[12];
  const float* Wy  = (const float*)d_in[13];
  const float* by  = (const float*)d_in[14];
  const float* Wf  = (const float*)d_in[15];
  const float* bf  = (const float*)d_in[16];
  const float* Wfa = (const float*)d_in[17];
  const float* bfa = (const float*)d_in[18];
  float* ws = (float*)d_ws;   // needs WS_END*4 ~= 1.24 MB
  float* out = (float*)d_out;

  prep_a<<<dim3(1111), dim3(256), 0, stream>>>(
      Wk, Wr, We1, be1, We2, be2, Wm, bm, Wy, by, Wf, bf, Wfa, bfa, ws);
  prep_b<<<dim3(4), dim3(256), 0, stream>>>(Wk, bl, ws);
  decode_main<<<dim3(BN / 8), dim3(512), 0, stream>>>(
      conditions, state_h, state_c, ws, out);
}

// Round 7
// 430.907 us; speedup vs baseline: 1.0208x; 1.0208x over previous
//
#include <hip/hip_runtime.h>
#include <stdint.h>
#include <math.h>

// Problem constants
#define BN 4096
#define TT 20
#define HH 256
#define EE 128
#define KK 5
#define NCOND 5

// ws layout (float indices)
#define WS_KEYS 0                       // 320 u32: per step, 4 heads x (k1.x,k1.y,k2.x,k2.y)
#define WS_TSC  512                     // 20*1024 cumulative ts@Wk[384:404]
#define WS_WTT  20992                   // 256*80 head weights transposed [q][o], o padded to 80
#define WS_BIAS 41472                   // 80 concat head biases (pad 0)
#define WS_T1   41552                   // 5*128  We1@We2
#define WS_EB2  42192                   // 128    be1@We2 + be2
#define WS_ZC   42320                   // 1024   (be1@We2+be2)@Wk1 + bl
#define WS_M    43344                   // 5*1024 We1@We2@Wk1
#define WS_WSUM 48464                   // 256*1024  Wk[128:384] + Wr
#define WS_END  310608                  // 1.24 MB

#define TINYF 1.17549435e-38f
#define LO_N  0.99999994f               // -nextafter(-1,0)
#define LOG2E 1.44269504f
#define LN2   0.69314718f

// ---------------- Threefry-2x32 (JAX-exact) ----------------
__device__ __forceinline__ void tf2(uint32_t k0, uint32_t k1, uint32_t x0, uint32_t x1,
                                    uint32_t& o0, uint32_t& o1) {
  const uint32_t ks2 = k0 ^ k1 ^ 0x1BD11BDAu;
  x0 += k0; x1 += k1;
#define RND(r) { x0 += x1; x1 = (x1 << (r)) | (x1 >> (32 - (r))); x1 ^= x0; }
  RND(13) RND(15) RND(26) RND(6)   x0 += k1;  x1 += ks2 + 1u;
  RND(17) RND(29) RND(16) RND(24)  x0 += ks2; x1 += k0 + 2u;
  RND(13) RND(15) RND(26) RND(6)   x0 += k0;  x1 += k1 + 3u;
  RND(17) RND(29) RND(16) RND(24)  x0 += k1;  x1 += ks2 + 4u;
  RND(13) RND(15) RND(26) RND(6)   x0 += ks2; x1 += k0 + 5u;
#undef RND
  o0 = x0; o1 = x1;
}

// jax_threefry_partitionable: bits[n] = a ^ b, (a,b) = threefry2x32(key, (0, n))
__device__ __forceinline__ uint32_t pbits(uint32_t k0, uint32_t k1, uint32_t n) {
  uint32_t a, b;
  tf2(k0, k1, 0u, n, a, b);
  return a ^ b;
}

__device__ __forceinline__ float u01f(uint32_t bits) {
  return __uint_as_float((bits >> 9) | 0x3f800000u) - 1.0f;
}

// ---- hardware transcendentals (v_exp_f32 / v_log_f32 / v_rcp_f32) ----
__device__ __forceinline__ float fexp(float x) { return __builtin_amdgcn_exp2f(x * LOG2E); }
__device__ __forceinline__ float flog(float x) { return __builtin_amdgcn_logf(x) * LN2; }
__device__ __forceinline__ float frcp(float x) { return __builtin_amdgcn_rcpf(x); }
__device__ __forceinline__ float fsig(float x) {
  return frcp(1.0f + __builtin_amdgcn_exp2f(-x * LOG2E));
}
__device__ __forceinline__ float ftanh(float x) {
  return 1.0f - 2.0f * frcp(1.0f + __builtin_amdgcn_exp2f(x * (2.0f * LOG2E)));
}

// XLA ErfInv32 (Giles polynomial), log via hw
__device__ __forceinline__ float erfinv_f(float x) {
  float w = -flog(fmaf(-x, x, 1.0f));
  float p;
  if (w < 5.0f) {
    w = w - 2.5f;
    p = 2.81022636e-08f;
    p = 3.43273939e-07f + p * w;
    p = -3.5233877e-06f + p * w;
    p = -4.39150654e-06f + p * w;
    p = 0.00021858087f  + p * w;
    p = -0.00125372503f + p * w;
    p = -0.00417768164f + p * w;
    p = 0.246640727f    + p * w;
    p = 1.50140941f     + p * w;
  } else {
    w = sqrtf(w) - 3.0f;
    p = -0.000200214257f;
    p = 0.000100950558f + p * w;
    p = 0.00134934322f  + p * w;
    p = -0.00367342844f + p * w;
    p = 0.00573950773f  + p * w;
    p = -0.0076224613f  + p * w;
    p = 0.00943887047f  + p * w;
    p = 1.00167406f     + p * w;
    p = 2.83297682f     + p * w;
  }
  return p * x;
}

// round-to-nearest-even f32 -> bf16 bits
__device__ __forceinline__ uint32_t bf16rne(float f) {
  uint32_t u = __float_as_uint(f);
  return (u + 0x7fffu + ((u >> 16) & 1u)) >> 16;
}

// ---------------- prep_a: keys, tsc, WTT/bias, T1/eb2, WSUM ----------------
__global__ __launch_bounds__(256) void prep_a(
    const float* __restrict__ Wk, const float* __restrict__ Wr,
    const float* __restrict__ We1, const float* __restrict__ be1,
    const float* __restrict__ We2, const float* __restrict__ be2,
    const float* __restrict__ Wm, const float* __restrict__ bm,
    const float* __restrict__ Wy, const float* __restrict__ by,
    const float* __restrict__ Wf, const float* __restrict__ bf,
    const float* __restrict__ Wfa, const float* __restrict__ bfa,
    float* __restrict__ ws) {
  const int bid = blockIdx.x, tid = threadIdx.x;
  if (bid == 0) {
    if (tid < 4) {
      uint32_t* keys = (uint32_t*)ws;
      const int l = tid;                 // 0=km 1=ky 2=kf 3=kfa
      uint32_t kx = 0u, ky = 42u;        // jax.random.key(42)
      for (int t = 0; t < TT; ++t) {
        uint32_t hx, hy;
        tf2(kx, ky, 0u, (uint32_t)(l + 1), hx, hy);
        uint32_t k1x, k1y, k2x, k2y;
        tf2(hx, hy, 0u, 0u, k1x, k1y);
        tf2(hx, hy, 0u, 1u, k2x, k2y);
        keys[t * 16 + l * 4 + 0] = k1x;
        keys[t * 16 + l * 4 + 1] = k1y;
        keys[t * 16 + l * 4 + 2] = k2x;
        keys[t * 16 + l * 4 + 3] = k2y;
        uint32_t nx, ny;
        tf2(kx, ky, 0u, 0u, nx, ny);
        kx = nx; ky = ny;
      }
    }
  } else if (bid <= 4) {
    const int col = (bid - 1) * 256 + tid;
    float s = 0.0f;
    for (int p = 0; p < TT; ++p) {
      s += Wk[(size_t)(EE + HH + p) * 1024 + col];
      ws[WS_TSC + p * 1024 + col] = s;
    }
  } else if (bid <= 84) {
    // WTT[q][o] transposed head weights, o-padded to 80 (zeros)
    const int idx = (bid - 5) * 256 + tid;   // < 20480
    const int q = idx / 80, o = idx - q * 80;
    float v = 0.0f;
    if (o < 30)      v = Wm[q * 30 + o];
    else if (o < 45) v = Wy[q * 15 + (o - 30)];
    else if (o < 60) v = Wf[q * 15 + (o - 45)];
    else if (o < 75) v = Wfa[q * 15 + (o - 60)];
    ws[WS_WTT + idx] = v;
  } else if (bid == 85) {
    if (tid < 80) {
      float v = 0.0f;
      if (tid < 30)      v = bm[tid];
      else if (tid < 45) v = by[tid - 30];
      else if (tid < 60) v = bf[tid - 45];
      else if (tid < 75) v = bfa[tid - 60];
      ws[WS_BIAS + tid] = v;
    }
  } else if (bid == 86) {
    // T1[c][q] = sum_e We1[c][e]*We2[e][q]; eb2[q] = be2[q] + sum_e be1[e]*We2[e][q]
    if (tid < EE) {
      const int q = tid;
      float t0 = 0.f, t1 = 0.f, t2 = 0.f, t3 = 0.f, t4 = 0.f;
      float eb = be2[q];
      for (int e = 0; e < EE; ++e) {
        const float w2 = We2[e * EE + q];
        t0 = fmaf(We1[0 * EE + e], w2, t0);
        t1 = fmaf(We1[1 * EE + e], w2, t1);
        t2 = fmaf(We1[2 * EE + e], w2, t2);
        t3 = fmaf(We1[3 * EE + e], w2, t3);
        t4 = fmaf(We1[4 * EE + e], w2, t4);
        eb = fmaf(be1[e], w2, eb);
      }
      ws[WS_T1 + 0 * EE + q] = t0;
      ws[WS_T1 + 1 * EE + q] = t1;
      ws[WS_T1 + 2 * EE + q] = t2;
      ws[WS_T1 + 3 * EE + q] = t3;
      ws[WS_T1 + 4 * EE + q] = t4;
      ws[WS_EB2 + q] = eb;
    }
  } else {
    // WSUM[q][col] = Wk[128+q][col] + Wr[q][col]
    const int idx = (bid - 87) * 256 + tid;
    if (idx < 256 * 1024) {
      const int q = idx >> 10, col = idx & 1023;
      ws[WS_WSUM + idx] = Wk[(size_t)(EE + q) * 1024 + col] + Wr[(size_t)q * 1024 + col];
    }
  }
}

// ---------------- prep_b: M = T1@Wk1 (5x1024), zc = eb2@Wk1 + bl ----------------
__global__ __launch_bounds__(256) void prep_b(
    const float* __restrict__ Wk, const float* __restrict__ bl,
    float* __restrict__ ws) {
  const int col = blockIdx.x * 256 + threadIdx.x;   // 0..1023
  float m0 = 0.f, m1 = 0.f, m2 = 0.f, m3 = 0.f, m4 = 0.f;
  float zacc = bl[col];
  for (int q = 0; q < EE; ++q) {
    const float wv = Wk[(size_t)q * 1024 + col];
    m0 = fmaf(ws[WS_T1 + 0 * EE + q], wv, m0);
    m1 = fmaf(ws[WS_T1 + 1 * EE + q], wv, m1);
    m2 = fmaf(ws[WS_T1 + 2 * EE + q], wv, m2);
    m3 = fmaf(ws[WS_T1 + 3 * EE + q], wv, m3);
    m4 = fmaf(ws[WS_T1 + 4 * EE + q], wv, m4);
    zacc = fmaf(ws[WS_EB2 + q], wv, zacc);
  }
  ws[WS_M + 0 * 1024 + col] = m0;
  ws[WS_M + 1 * 1024 + col] = m1;
  ws[WS_M + 2 * 1024 + col] = m2;
  ws[WS_M + 3 * 1024 + col] = m3;
  ws[WS_M + 4 * 1024 + col] = m4;
  ws[WS_ZC + col] = zacc;
}

// ---------------- main: 8 rows/block, 512 blocks, 20 steps ----------------
// Phase A: thread (u = tid&255, half = tid>>8) -> 4 rows x unit u.
// Phase B: wave ch = tid>>6 owns q-chunk [32ch,32ch+32); lane pr = tid&63 (pr<38)
//          owns outputs {2pr, 2pr+1}; weights bf16-packed in 32 persistent VGPRs.
// Phase C: tid<256: lane = (row r, head, k) with 8-lane shfl groups.
__global__ __launch_bounds__(512, 4) void decode_main(
    const float* __restrict__ conditions, const float* __restrict__ state_h,
    const float* __restrict__ state_c, const float* __restrict__ ws,
    float* __restrict__ out) {
  __shared__ float Msh[5 * 1024];       // 20 KB
  __shared__ float hsh[8 * HH];         // 8 KB: state_h staging -> h
  __shared__ float pp[8][8][80];        // 20 KB head partials per q-chunk
  __shared__ float psh[8 * 80];         // 2.5 KB head outputs
  __shared__ float biasL[80];
  __shared__ float conds[8 * 8];
  __shared__ uint32_t keysL[TT * 16];

  const int tid = threadIdx.x;
  const int row0 = blockIdx.x * 8;
  const int u = tid & 255;
  const int half = tid >> 8;
  const int rbase = half * 4;

  // ---- prologue staging ----
  for (int i = tid; i < 5 * 1024; i += 512) Msh[i] = ws[WS_M + i];
  if (tid < 80) biasL[tid] = ws[WS_BIAS + tid];
  for (int i = tid; i < TT * 16; i += 512) keysL[i] = ((const uint32_t*)ws)[WS_KEYS + i];
  if (tid < 8 * NCOND) {
    const int r = tid / NCOND, c = tid - r * NCOND;
    conds[r * 8 + c] = conditions[(size_t)(row0 + r) * (TT * NCOND) + c];  // [:,0,:]
  }
  for (int i = tid; i < 8 * HH; i += 512) hsh[i] = state_h[(size_t)row0 * HH + i];

  // ---- persistent bf16-packed head weights: UNCONDITIONAL load (index-clamped) ----
  const int ch = tid >> 6;              // q-chunk 0..7 (uniform per wave)
  const int pr = tid & 63;              // output pair
  const bool bact = (pr < 38);
  const int oA = bact ? 2 * pr : 0;     // clamped for inactive lanes
  const int oB = bact ? 2 * pr + 1 : 1; // oB<=75 (75 is zero pad column)
  uint32_t wp0[16], wp1[16];
#pragma unroll
  for (int j2 = 0; j2 < 16; ++j2) {
    const int q = ch * 32 + 2 * j2;
    wp0[j2] = bf16rne(ws[WS_WTT + q * 80 + oA]) |
              (bf16rne(ws[WS_WTT + (q + 1) * 80 + oA]) << 16);
    wp1[j2] = bf16rne(ws[WS_WTT + q * 80 + oB]) |
              (bf16rne(ws[WS_WTT + (q + 1) * 80 + oB]) << 16);
  }

  float sc[4];
#pragma unroll
  for (int rr = 0; rr < 4; ++rr) sc[rr] = state_c[(size_t)(row0 + rbase + rr) * HH + u];
  __syncthreads();

  // ---- step-invariant cz[gate][row] = zc + state_h @ WSUM (exact fp32) ----
  float cz[4][4];
#pragma unroll
  for (int g = 0; g < 4; ++g) {
    const float z = ws[WS_ZC + g * 256 + u];
#pragma unroll
    for (int rr = 0; rr < 4; ++rr) cz[g][rr] = z;
  }
  for (int q = 0; q < HH; ++q) {
    const float w0 = ws[WS_WSUM + q * 1024 + u];
    const float w1 = ws[WS_WSUM + q * 1024 + 256 + u];
    const float w2 = ws[WS_WSUM + q * 1024 + 512 + u];
    const float w3 = ws[WS_WSUM + q * 1024 + 768 + u];
#pragma unroll
    for (int rr = 0; rr < 4; ++rr) {
      const float e = hsh[(rbase + rr) * HH + q];
      cz[0][rr] = fmaf(e, w0, cz[0][rr]);
      cz[1][rr] = fmaf(e, w1, cz[1][rr]);
      cz[2][rr] = fmaf(e, w2, cz[2][rr]);
      cz[3][rr] = fmaf(e, w3, cz[3][rr]);
    }
  }
  __syncthreads();   // hsh(state_h) dead -> h buffer

  for (int t = 0; t < TT; ++t) {
    // ---- Phase A: z = cond@M + cz + tsc[t]; gates -> h -> hsh ----
    {
      const float ts0 = ws[WS_TSC + t * 1024 + u];
      const float ts1 = ws[WS_TSC + t * 1024 + 256 + u];
      const float ts2 = ws[WS_TSC + t * 1024 + 512 + u];
      const float ts3 = ws[WS_TSC + t * 1024 + 768 + u];
      float mA[5], mB[5], mC[5], mD[5];
#pragma unroll
      for (int c = 0; c < 5; ++c) {
        mA[c] = Msh[c * 1024 + u];
        mB[c] = Msh[c * 1024 + 256 + u];
        mC[c] = Msh[c * 1024 + 512 + u];
        mD[c] = Msh[c * 1024 + 768 + u];
      }
#pragma unroll
      for (int rr = 0; rr < 4; ++rr) {
        const int row = rbase + rr;
        const float c0 = conds[row * 8 + 0], c1 = conds[row * 8 + 1], c2 = conds[row * 8 + 2],
                    c3 = conds[row * 8 + 3], c4 = conds[row * 8 + 4];
        float zi = cz[0][rr] + ts0, zf = cz[1][rr] + ts1,
              zg = cz[2][rr] + ts2, zo = cz[3][rr] + ts3;
        zi = fmaf(c0, mA[0], zi); zi = fmaf(c1, mA[1], zi); zi = fmaf(c2, mA[2], zi);
        zi = fmaf(c3, mA[3], zi); zi = fmaf(c4, mA[4], zi);
        zf = fmaf(c0, mB[0], zf); zf = fmaf(c1, mB[1], zf); zf = fmaf(c2, mB[2], zf);
        zf = fmaf(c3, mB[3], zf); zf = fmaf(c4, mB[4], zf);
        zg = fmaf(c0, mC[0], zg); zg = fmaf(c1, mC[1], zg); zg = fmaf(c2, mC[2], zg);
        zg = fmaf(c3, mC[3], zg); zg = fmaf(c4, mC[4], zg);
        zo = fmaf(c0, mD[0], zo); zo = fmaf(c1, mD[1], zo); zo = fmaf(c2, mD[2], zo);
        zo = fmaf(c3, mD[3], zo); zo = fmaf(c4, mD[4], zo);
        const float cv = fsig(zf) * sc[rr] + fsig(zi) * ftanh(zg);
        const float hv = fsig(zo) * ftanh(cv);
        hsh[row * HH + u] = hv;
      }
    }
    __syncthreads();
    // ---- Phase B: 2 outputs x 32-q chunk from register weights (broadcast h reads) ----
    {
      float a0[8], a1[8];
#pragma unroll
      for (int r = 0; r < 8; ++r) { a0[r] = 0.0f; a1[r] = 0.0f; }
      const float4* h4 = (const float4*)hsh;
#pragma unroll
      for (int j4 = 0; j4 < 8; ++j4) {
        const uint32_t pa = wp0[2 * j4], pb = wp0[2 * j4 + 1];
        const uint32_t qa = wp1[2 * j4], qb = wp1[2 * j4 + 1];
        const float w00 = __uint_as_float(pa << 16);
        const float w01 = __uint_as_float(pa & 0xffff0000u);
        const float w02 = __uint_as_float(pb << 16);
        const float w03 = __uint_as_float(pb & 0xffff0000u);
        const float w10 = __uint_as_float(qa << 16);
        const float w11 = __uint_as_float(qa & 0xffff0000u);
        const float w12 = __uint_as_float(qb << 16);
        const float w13 = __uint_as_float(qb & 0xffff0000u);
#pragma unroll
        for (int r = 0; r < 8; ++r) {
          const float4 hv = h4[r * 64 + ch * 8 + j4];
          a0[r] = fmaf(hv.x, w00, a0[r]);
          a0[r] = fmaf(hv.y, w01, a0[r]);
          a0[r] = fmaf(hv.z, w02, a0[r]);
          a0[r] = fmaf(hv.w, w03, a0[r]);
          a1[r] = fmaf(hv.x, w10, a1[r]);
          a1[r] = fmaf(hv.y, w11, a1[r]);
          a1[r] = fmaf(hv.z, w12, a1[r]);
          a1[r] = fmaf(hv.w, w13, a1[r]);
        }
      }
      if (bact) {
#pragma unroll
        for (int r = 0; r < 8; ++r) {
          *(float2*)&pp[ch][r][2 * pr] = make_float2(a0[r], a1[r]);
        }
      }
    }
    __syncthreads();
    // ---- reduce partials: psh[r][o] = bias + sum_ch pp ----
    for (int s = tid; s < 640; s += 512) {
      const int rr = s / 80, o = s - rr * 80;
      if (o < 76) {
        float acc = biasL[o];
#pragma unroll
        for (int c = 0; c < 8; ++c) acc += pp[c][rr][o];
        psh[rr * 80 + o] = acc;
      }
    }
    __syncthreads();
    // ---- Phase C: wave-parallel sampling; lane = (r, head, k) ----
    if (tid < 256) {
      const int g8 = tid >> 3, k = tid & 7;
      const int r = g8 >> 2, head = g8 & 3;
      const int row = row0 + r;
      const int base = head ? (30 + 15 * (head - 1)) : 0;
      const uint32_t g0 = keysL[t * 16 + head * 4 + 0], g1 = keysL[t * 16 + head * 4 + 1];
      const uint32_t n0 = keysL[t * 16 + head * 4 + 2], n1 = keysL[t * 16 + head * 4 + 3];
      const float lk = (k < 5) ? psh[r * 80 + base + k] : -INFINITY;
      float mx = fmaxf(lk, __shfl_xor(lk, 1));
      mx = fmaxf(mx, __shfl_xor(mx, 2));
      mx = fmaxf(mx, __shfl_xor(mx, 4));
      const float ek = (k < 5) ? fexp(lk - mx) : 0.0f;
      float ss = ek + __shfl_xor(ek, 1);
      ss += __shfl_xor(ss, 2);
      ss += __shfl_xor(ss, 4);
      const float rss = frcp(ss);
      // gumbel argmax, first-max-wins
      float v = -INFINITY;
      if (k < 5) {
        float uv = u01f(pbits(g0, g1, (uint32_t)(row * 5 + k)));
        uv = fmaxf(TINYF, uv * (1.0f - TINYF) + TINYF);
        v = lk - flog(-flog(uv));
      }
      float vm = fmaxf(v, __shfl_xor(v, 1));
      vm = fmaxf(vm, __shfl_xor(vm, 2));
      vm = fmaxf(vm, __shfl_xor(vm, 4));
      int cand = (v == vm) ? k : 8;
      cand = min(cand, __shfl_xor(cand, 1));
      cand = min(cand, __shfl_xor(cand, 2));
      cand = min(cand, __shfl_xor(cand, 4));
      const int idx = cand;
      const size_t ob = head
          ? ((size_t)BN * TT * 30 + (size_t)(head - 1) * BN * TT * 15 + ((size_t)row * TT + t) * 15)
          : ((size_t)row * TT + t) * 30;
      if (k < 5) {
        out[ob + k] = ek * rss;
        out[ob + 5 + k] = psh[r * 80 + base + 5 + k];
        out[ob + 10 + k] = fexp(psh[r * 80 + base + 10 + k]);
        if (head == 0) {
          out[ob + 15 + k] = psh[r * 80 + 15 + k];
          out[ob + 20 + k] = fexp(psh[r * 80 + 20 + k]);
          out[ob + 25 + k] = ftanh(psh[r * 80 + 25 + k]);
        }
      }
      if (k == 0) {
        if (head == 0) {
          float uz0 = u01f(pbits(n0, n1, (uint32_t)(row * 2 + 0))) * 2.0f - LO_N;
          float uz1 = u01f(pbits(n0, n1, (uint32_t)(row * 2 + 1))) * 2.0f - LO_N;
          uz0 = fmaxf(-LO_N, uz0); uz1 = fmaxf(-LO_N, uz1);
          const float z0 = 1.41421356f * erfinv_f(uz0);
          const float z1 = 1.41421356f * erfinv_f(uz1);
          const float mu = psh[r * 80 + 5 + idx];
          const float sl = fexp(psh[r * 80 + 10 + idx]);
          const float mula = psh[r * 80 + 15 + idx];
          const float sla = fexp(psh[r * 80 + 20 + idx]);
          const float rho = ftanh(psh[r * 80 + 25 + idx]);
          conds[r * 8 + 0] = mu + sl * z0;
          conds[r * 8 + 1] = mula + sla * (rho * z0 + sqrtf(1.0f - rho * rho) * z1);
        } else {
          float uz = u01f(pbits(n0, n1, (uint32_t)row)) * 2.0f - LO_N;
          uz = fmaxf(-LO_N, uz);
          const float zz = 1.41421356f * erfinv_f(uz);
          conds[r * 8 + 1 + head] =
              psh[r * 80 + base + 5 + idx] + fexp(psh[r * 80 + base + 10 + idx]) * zz;
        }
      }
    }
    __syncthreads();
  }
}

extern "C" void kernel_launch(void* const* d_in, const int* in_sizes, int n_in,
                              void* d_out, int out_size, void* d_ws, size_t ws_size,
                              hipStream_t stream) {
  const float* conditions = (const float*)d_in[0];
  const float* state_h = (const float*)d_in[1];
  const float* state_c = (const float*)d_in[2];
  // d_in[3] = steps_n (=20, compile-time TT)
  const float* We1 = (const float*)d_in[4];
  const float* be1 = (const float*)d_in[5];
  const float* We2 = (const float*)d_in[6];
  const float* be2 = (const float*)d_in[7];
  const float* Wk  = (const float*)d_in[8];
  const float* Wr  = (const float*)d_in[9];
  const float* bl  = (const float*)d_in[10];
  const float* Wm  = (const float*)d_in[11];
  const float* bm  = (const float*)d_in[12];
  const float* Wy  = (const float*)d_in[13];
  const float* by  = (const float*)d_in[14];
  const float* Wf  = (const float*)d_in[15];
  const float* bf  = (const float*)d_in[16];
  const float* Wfa = (const float*)d_in[17];
  const float* bfa = (const float*)d_in[18];
  float* ws = (float*)d_ws;   // needs WS_END*4 ~= 1.24 MB
  float* out = (float*)d_out;

  prep_a<<<dim3(1111), dim3(256), 0, stream>>>(
      Wk, Wr, We1, be1, We2, be2, Wm, bm, Wy, by, Wf, bf, Wfa, bfa, ws);
  prep_b<<<dim3(4), dim3(256), 0, stream>>>(Wk, bl, ws);
  decode_main<<<dim3(BN / 8), dim3(512), 0, stream>>>(
      conditions, state_h, state_c, ws, out);
}

// Round 8
// 399.359 us; speedup vs baseline: 1.1014x; 1.0790x over previous
//
#include <hip/hip_runtime.h>
#include <stdint.h>
#include <math.h>

// Problem constants
#define BN 4096
#define TT 20
#define HH 256
#define EE 128
#define KK 5
#define NCOND 5

// ws layout (float indices)
#define WS_KEYS 0                       // 320 u32: per step, 4 heads x (k1.x,k1.y,k2.x,k2.y)
#define WS_TSC  512                     // 20*1024 cumulative ts@Wk[384:404]
#define WS_WTT  20992                   // 256*80 head weights transposed [q][o], o padded to 80
#define WS_BIAS 41472                   // 80 concat head biases (pad 0)
#define WS_T1   41552                   // 5*128  We1@We2
#define WS_EB2  42192                   // 128    be1@We2 + be2
#define WS_ZC   42320                   // 1024   (be1@We2+be2)@Wk1 + bl
#define WS_M    43344                   // 5*1024 We1@We2@Wk1
#define WS_WSUM 48464                   // 256*1024  Wk[128:384] + Wr
#define WS_END  310608                  // 1.24 MB

#define TINYF 1.17549435e-38f
#define LO_N  0.99999994f               // -nextafter(-1,0)
#define LOG2E 1.44269504f
#define LN2   0.69314718f

// ---------------- Threefry-2x32 (JAX-exact) ----------------
__device__ __forceinline__ void tf2(uint32_t k0, uint32_t k1, uint32_t x0, uint32_t x1,
                                    uint32_t& o0, uint32_t& o1) {
  const uint32_t ks2 = k0 ^ k1 ^ 0x1BD11BDAu;
  x0 += k0; x1 += k1;
#define RND(r) { x0 += x1; x1 = (x1 << (r)) | (x1 >> (32 - (r))); x1 ^= x0; }
  RND(13) RND(15) RND(26) RND(6)   x0 += k1;  x1 += ks2 + 1u;
  RND(17) RND(29) RND(16) RND(24)  x0 += ks2; x1 += k0 + 2u;
  RND(13) RND(15) RND(26) RND(6)   x0 += k0;  x1 += k1 + 3u;
  RND(17) RND(29) RND(16) RND(24)  x0 += k1;  x1 += ks2 + 4u;
  RND(13) RND(15) RND(26) RND(6)   x0 += ks2; x1 += k0 + 5u;
#undef RND
  o0 = x0; o1 = x1;
}

// jax_threefry_partitionable: bits[n] = a ^ b, (a,b) = threefry2x32(key, (0, n))
__device__ __forceinline__ uint32_t pbits(uint32_t k0, uint32_t k1, uint32_t n) {
  uint32_t a, b;
  tf2(k0, k1, 0u, n, a, b);
  return a ^ b;
}

__device__ __forceinline__ float u01f(uint32_t bits) {
  return __uint_as_float((bits >> 9) | 0x3f800000u) - 1.0f;
}

// ---- hardware transcendentals (v_exp_f32 / v_log_f32 / v_rcp_f32) ----
__device__ __forceinline__ float fexp(float x) { return __builtin_amdgcn_exp2f(x * LOG2E); }
__device__ __forceinline__ float flog(float x) { return __builtin_amdgcn_logf(x) * LN2; }
__device__ __forceinline__ float frcp(float x) { return __builtin_amdgcn_rcpf(x); }
__device__ __forceinline__ float fsig(float x) {
  return frcp(1.0f + __builtin_amdgcn_exp2f(-x * LOG2E));
}
__device__ __forceinline__ float ftanh(float x) {
  return 1.0f - 2.0f * frcp(1.0f + __builtin_amdgcn_exp2f(x * (2.0f * LOG2E)));
}

// XLA ErfInv32 (Giles polynomial), log via hw
__device__ __forceinline__ float erfinv_f(float x) {
  float w = -flog(fmaf(-x, x, 1.0f));
  float p;
  if (w < 5.0f) {
    w = w - 2.5f;
    p = 2.81022636e-08f;
    p = 3.43273939e-07f + p * w;
    p = -3.5233877e-06f + p * w;
    p = -4.39150654e-06f + p * w;
    p = 0.00021858087f  + p * w;
    p = -0.00125372503f + p * w;
    p = -0.00417768164f + p * w;
    p = 0.246640727f    + p * w;
    p = 1.50140941f     + p * w;
  } else {
    w = sqrtf(w) - 3.0f;
    p = -0.000200214257f;
    p = 0.000100950558f + p * w;
    p = 0.00134934322f  + p * w;
    p = -0.00367342844f + p * w;
    p = 0.00573950773f  + p * w;
    p = -0.0076224613f  + p * w;
    p = 0.00943887047f  + p * w;
    p = 1.00167406f     + p * w;
    p = 2.83297682f     + p * w;
  }
  return p * x;
}

// round-to-nearest-even f32 -> bf16 bits
__device__ __forceinline__ uint32_t bf16rne(float f) {
  uint32_t u = __float_as_uint(f);
  return (u + 0x7fffu + ((u >> 16) & 1u)) >> 16;
}

// ---------------- prep_a: keys, tsc, WTT/bias, T1/eb2, WSUM ----------------
__global__ __launch_bounds__(256) void prep_a(
    const float* __restrict__ Wk, const float* __restrict__ Wr,
    const float* __restrict__ We1, const float* __restrict__ be1,
    const float* __restrict__ We2, const float* __restrict__ be2,
    const float* __restrict__ Wm, const float* __restrict__ bm,
    const float* __restrict__ Wy, const float* __restrict__ by,
    const float* __restrict__ Wf, const float* __restrict__ bf,
    const float* __restrict__ Wfa, const float* __restrict__ bfa,
    float* __restrict__ ws) {
  const int bid = blockIdx.x, tid = threadIdx.x;
  if (bid == 0) {
    if (tid < 4) {
      uint32_t* keys = (uint32_t*)ws;
      const int l = tid;                 // 0=km 1=ky 2=kf 3=kfa
      uint32_t kx = 0u, ky = 42u;        // jax.random.key(42)
      for (int t = 0; t < TT; ++t) {
        uint32_t hx, hy;
        tf2(kx, ky, 0u, (uint32_t)(l + 1), hx, hy);
        uint32_t k1x, k1y, k2x, k2y;
        tf2(hx, hy, 0u, 0u, k1x, k1y);
        tf2(hx, hy, 0u, 1u, k2x, k2y);
        keys[t * 16 + l * 4 + 0] = k1x;
        keys[t * 16 + l * 4 + 1] = k1y;
        keys[t * 16 + l * 4 + 2] = k2x;
        keys[t * 16 + l * 4 + 3] = k2y;
        uint32_t nx, ny;
        tf2(kx, ky, 0u, 0u, nx, ny);
        kx = nx; ky = ny;
      }
    }
  } else if (bid <= 4) {
    const int col = (bid - 1) * 256 + tid;
    float s = 0.0f;
    for (int p = 0; p < TT; ++p) {
      s += Wk[(size_t)(EE + HH + p) * 1024 + col];
      ws[WS_TSC + p * 1024 + col] = s;
    }
  } else if (bid <= 84) {
    // WTT[q][o] transposed head weights, o-padded to 80 (zeros)
    const int idx = (bid - 5) * 256 + tid;   // < 20480
    const int q = idx / 80, o = idx - q * 80;
    float v = 0.0f;
    if (o < 30)      v = Wm[q * 30 + o];
    else if (o < 45) v = Wy[q * 15 + (o - 30)];
    else if (o < 60) v = Wf[q * 15 + (o - 45)];
    else if (o < 75) v = Wfa[q * 15 + (o - 60)];
    ws[WS_WTT + idx] = v;
  } else if (bid == 85) {
    if (tid < 80) {
      float v = 0.0f;
      if (tid < 30)      v = bm[tid];
      else if (tid < 45) v = by[tid - 30];
      else if (tid < 60) v = bf[tid - 45];
      else if (tid < 75) v = bfa[tid - 60];
      ws[WS_BIAS + tid] = v;
    }
  } else if (bid == 86) {
    // T1[c][q] = sum_e We1[c][e]*We2[e][q]; eb2[q] = be2[q] + sum_e be1[e]*We2[e][q]
    if (tid < EE) {
      const int q = tid;
      float t0 = 0.f, t1 = 0.f, t2 = 0.f, t3 = 0.f, t4 = 0.f;
      float eb = be2[q];
      for (int e = 0; e < EE; ++e) {
        const float w2 = We2[e * EE + q];
        t0 = fmaf(We1[0 * EE + e], w2, t0);
        t1 = fmaf(We1[1 * EE + e], w2, t1);
        t2 = fmaf(We1[2 * EE + e], w2, t2);
        t3 = fmaf(We1[3 * EE + e], w2, t3);
        t4 = fmaf(We1[4 * EE + e], w2, t4);
        eb = fmaf(be1[e], w2, eb);
      }
      ws[WS_T1 + 0 * EE + q] = t0;
      ws[WS_T1 + 1 * EE + q] = t1;
      ws[WS_T1 + 2 * EE + q] = t2;
      ws[WS_T1 + 3 * EE + q] = t3;
      ws[WS_T1 + 4 * EE + q] = t4;
      ws[WS_EB2 + q] = eb;
    }
  } else {
    // WSUM[q][col] = Wk[128+q][col] + Wr[q][col]
    const int idx = (bid - 87) * 256 + tid;
    if (idx < 256 * 1024) {
      const int q = idx >> 10, col = idx & 1023;
      ws[WS_WSUM + idx] = Wk[(size_t)(EE + q) * 1024 + col] + Wr[(size_t)q * 1024 + col];
    }
  }
}

// ---------------- prep_b: M = T1@Wk1 (5x1024), zc = eb2@Wk1 + bl ----------------
__global__ __launch_bounds__(256) void prep_b(
    const float* __restrict__ Wk, const float* __restrict__ bl,
    float* __restrict__ ws) {
  const int col = blockIdx.x * 256 + threadIdx.x;   // 0..1023
  float m0 = 0.f, m1 = 0.f, m2 = 0.f, m3 = 0.f, m4 = 0.f;
  float zacc = bl[col];
  for (int q = 0; q < EE; ++q) {
    const float wv = Wk[(size_t)q * 1024 + col];
    m0 = fmaf(ws[WS_T1 + 0 * EE + q], wv, m0);
    m1 = fmaf(ws[WS_T1 + 1 * EE + q], wv, m1);
    m2 = fmaf(ws[WS_T1 + 2 * EE + q], wv, m2);
    m3 = fmaf(ws[WS_T1 + 3 * EE + q], wv, m3);
    m4 = fmaf(ws[WS_T1 + 4 * EE + q], wv, m4);
    zacc = fmaf(ws[WS_EB2 + q], wv, zacc);
  }
  ws[WS_M + 0 * 1024 + col] = m0;
  ws[WS_M + 1 * 1024 + col] = m1;
  ws[WS_M + 2 * 1024 + col] = m2;
  ws[WS_M + 3 * 1024 + col] = m3;
  ws[WS_M + 4 * 1024 + col] = m4;
  ws[WS_ZC + col] = zacc;
}

// ---------------- main: 8 rows/block, 512 blocks, 20 steps ----------------
// amdgpu_waves_per_eu(4,4): pin allocator to 4 waves/EU -> 128-VGPR budget,
// so the 32 packed weight words stay register-resident (no scratch).
// Phase A: thread (u = tid&255, half = tid>>8) -> 4 rows x unit u.
// Phase B: wave ch = tid>>6 owns q-chunk [32ch,+32); lane pr = tid&63 (pr<38)
//          owns outputs {2pr,2pr+1}; weights bf16-packed in 32 persistent VGPRs.
// Phase C: tid<256: lane = (row r, head, k) with 8-lane shfl groups.
__global__ void __launch_bounds__(512)
__attribute__((amdgpu_waves_per_eu(4, 4)))
decode_main(
    const float* __restrict__ conditions, const float* __restrict__ state_h,
    const float* __restrict__ state_c, const float* __restrict__ ws,
    float* __restrict__ out) {
  __shared__ float Msh[5 * 1024];       // 20 KB
  __shared__ float hsh[8 * HH];         // 8 KB: state_h staging -> h
  __shared__ float pp[8][8][80];        // 20 KB head partials per q-chunk
  __shared__ float psh[8 * 80];         // 2.5 KB head outputs
  __shared__ float biasL[80];
  __shared__ float conds[8 * 8];
  __shared__ uint32_t keysL[TT * 16];

  const int tid = threadIdx.x;
  const int row0 = blockIdx.x * 8;
  const int u = tid & 255;
  const int half = tid >> 8;
  const int rbase = half * 4;

  // ---- prologue staging ----
  for (int i = tid; i < 5 * 1024; i += 512) Msh[i] = ws[WS_M + i];
  if (tid < 80) biasL[tid] = ws[WS_BIAS + tid];
  for (int i = tid; i < TT * 16; i += 512) keysL[i] = ((const uint32_t*)ws)[WS_KEYS + i];
  if (tid < 8 * NCOND) {
    const int r = tid / NCOND, c = tid - r * NCOND;
    conds[r * 8 + c] = conditions[(size_t)(row0 + r) * (TT * NCOND) + c];  // [:,0,:]
  }
  for (int i = tid; i < 8 * HH; i += 512) hsh[i] = state_h[(size_t)row0 * HH + i];

  // ---- persistent bf16-packed head weights: UNCONDITIONAL load + VGPR pin ----
  const int ch = tid >> 6;              // q-chunk 0..7 (uniform per wave)
  const int pr = tid & 63;              // output pair
  const bool bact = (pr < 38);
  const int oA = bact ? 2 * pr : 0;     // clamped for inactive lanes
  const int oB = bact ? 2 * pr + 1 : 1; // oB<=75 (75 is zero pad column)
  uint32_t wp0[16], wp1[16];
#pragma unroll
  for (int j2 = 0; j2 < 16; ++j2) {
    const int q = ch * 32 + 2 * j2;
    wp0[j2] = bf16rne(ws[WS_WTT + q * 80 + oA]) |
              (bf16rne(ws[WS_WTT + (q + 1) * 80 + oA]) << 16);
    wp1[j2] = bf16rne(ws[WS_WTT + q * 80 + oB]) |
              (bf16rne(ws[WS_WTT + (q + 1) * 80 + oB]) << 16);
  }
#pragma unroll
  for (int j2 = 0; j2 < 16; ++j2) {
    asm volatile("" : "+v"(wp0[j2]));
    asm volatile("" : "+v"(wp1[j2]));
  }

  float sc[4];
#pragma unroll
  for (int rr = 0; rr < 4; ++rr) sc[rr] = state_c[(size_t)(row0 + rbase + rr) * HH + u];
  __syncthreads();

  // ---- step-invariant cz[gate][row] = zc + state_h @ WSUM (exact fp32) ----
  float cz[4][4];
#pragma unroll
  for (int g = 0; g < 4; ++g) {
    const float z = ws[WS_ZC + g * 256 + u];
#pragma unroll
    for (int rr = 0; rr < 4; ++rr) cz[g][rr] = z;
  }
  for (int q = 0; q < HH; ++q) {
    const float w0 = ws[WS_WSUM + q * 1024 + u];
    const float w1 = ws[WS_WSUM + q * 1024 + 256 + u];
    const float w2 = ws[WS_WSUM + q * 1024 + 512 + u];
    const float w3 = ws[WS_WSUM + q * 1024 + 768 + u];
#pragma unroll
    for (int rr = 0; rr < 4; ++rr) {
      const float e = hsh[(rbase + rr) * HH + q];
      cz[0][rr] = fmaf(e, w0, cz[0][rr]);
      cz[1][rr] = fmaf(e, w1, cz[1][rr]);
      cz[2][rr] = fmaf(e, w2, cz[2][rr]);
      cz[3][rr] = fmaf(e, w3, cz[3][rr]);
    }
  }
  __syncthreads();   // hsh(state_h) dead -> h buffer

  for (int t = 0; t < TT; ++t) {
    // ---- Phase A: z = cond@M + cz + tsc[t]; gates -> h -> hsh ----
    {
      const float ts0 = ws[WS_TSC + t * 1024 + u];
      const float ts1 = ws[WS_TSC + t * 1024 + 256 + u];
      const float ts2 = ws[WS_TSC + t * 1024 + 512 + u];
      const float ts3 = ws[WS_TSC + t * 1024 + 768 + u];
      float mA[5], mB[5], mC[5], mD[5];
#pragma unroll
      for (int c = 0; c < 5; ++c) {
        mA[c] = Msh[c * 1024 + u];
        mB[c] = Msh[c * 1024 + 256 + u];
        mC[c] = Msh[c * 1024 + 512 + u];
        mD[c] = Msh[c * 1024 + 768 + u];
      }
#pragma unroll
      for (int rr = 0; rr < 4; ++rr) {
        const int row = rbase + rr;
        const float c0 = conds[row * 8 + 0], c1 = conds[row * 8 + 1], c2 = conds[row * 8 + 2],
                    c3 = conds[row * 8 + 3], c4 = conds[row * 8 + 4];
        float zi = cz[0][rr] + ts0, zf = cz[1][rr] + ts1,
              zg = cz[2][rr] + ts2, zo = cz[3][rr] + ts3;
        zi = fmaf(c0, mA[0], zi); zi = fmaf(c1, mA[1], zi); zi = fmaf(c2, mA[2], zi);
        zi = fmaf(c3, mA[3], zi); zi = fmaf(c4, mA[4], zi);
        zf = fmaf(c0, mB[0], zf); zf = fmaf(c1, mB[1], zf); zf = fmaf(c2, mB[2], zf);
        zf = fmaf(c3, mB[3], zf); zf = fmaf(c4, mB[4], zf);
        zg = fmaf(c0, mC[0], zg); zg = fmaf(c1, mC[1], zg); zg = fmaf(c2, mC[2], zg);
        zg = fmaf(c3, mC[3], zg); zg = fmaf(c4, mC[4], zg);
        zo = fmaf(c0, mD[0], zo); zo = fmaf(c1, mD[1], zo); zo = fmaf(c2, mD[2], zo);
        zo = fmaf(c3, mD[3], zo); zo = fmaf(c4, mD[4], zo);
        const float cv = fsig(zf) * sc[rr] + fsig(zi) * ftanh(zg);
        const float hv = fsig(zo) * ftanh(cv);
        hsh[row * HH + u] = hv;
      }
    }
    __syncthreads();
    // ---- Phase B: 2 outputs x 32-q chunk from register weights (broadcast h reads) ----
    {
      float a0[8], a1[8];
#pragma unroll
      for (int r = 0; r < 8; ++r) { a0[r] = 0.0f; a1[r] = 0.0f; }
      const float4* h4 = (const float4*)hsh;
#pragma unroll
      for (int j4 = 0; j4 < 8; ++j4) {
        const uint32_t pa = wp0[2 * j4], pb = wp0[2 * j4 + 1];
        const uint32_t qa = wp1[2 * j4], qb = wp1[2 * j4 + 1];
        const float w00 = __uint_as_float(pa << 16);
        const float w01 = __uint_as_float(pa & 0xffff0000u);
        const float w02 = __uint_as_float(pb << 16);
        const float w03 = __uint_as_float(pb & 0xffff0000u);
        const float w10 = __uint_as_float(qa << 16);
        const float w11 = __uint_as_float(qa & 0xffff0000u);
        const float w12 = __uint_as_float(qb << 16);
        const float w13 = __uint_as_float(qb & 0xffff0000u);
#pragma unroll
        for (int r = 0; r < 8; ++r) {
          const float4 hv = h4[r * 64 + ch * 8 + j4];
          a0[r] = fmaf(hv.x, w00, a0[r]);
          a0[r] = fmaf(hv.y, w01, a0[r]);
          a0[r] = fmaf(hv.z, w02, a0[r]);
          a0[r] = fmaf(hv.w, w03, a0[r]);
          a1[r] = fmaf(hv.x, w10, a1[r]);
          a1[r] = fmaf(hv.y, w11, a1[r]);
          a1[r] = fmaf(hv.z, w12, a1[r]);
          a1[r] = fmaf(hv.w, w13, a1[r]);
        }
      }
      if (bact) {
#pragma unroll
        for (int r = 0; r < 8; ++r) {
          *(float2*)&pp[ch][r][2 * pr] = make_float2(a0[r], a1[r]);
        }
      }
    }
    __syncthreads();
    // ---- reduce partials: psh[r][o] = bias + sum_ch pp ----
    for (int s = tid; s < 640; s += 512) {
      const int rr = s / 80, o = s - rr * 80;
      if (o < 76) {
        float acc = biasL[o];
#pragma unroll
        for (int c = 0; c < 8; ++c) acc += pp[c][rr][o];
        psh[rr * 80 + o] = acc;
      }
    }
    __syncthreads();
    // ---- Phase C: wave-parallel sampling; lane = (r, head, k) ----
    if (tid < 256) {
      const int g8 = tid >> 3, k = tid & 7;
      const int r = g8 >> 2, head = g8 & 3;
      const int row = row0 + r;
      const int base = head ? (30 + 15 * (head - 1)) : 0;
      const uint32_t g0 = keysL[t * 16 + head * 4 + 0], g1 = keysL[t * 16 + head * 4 + 1];
      const uint32_t n0 = keysL[t * 16 + head * 4 + 2], n1 = keysL[t * 16 + head * 4 + 3];
      const float lk = (k < 5) ? psh[r * 80 + base + k] : -INFINITY;
      float mx = fmaxf(lk, __shfl_xor(lk, 1));
      mx = fmaxf(mx, __shfl_xor(mx, 2));
      mx = fmaxf(mx, __shfl_xor(mx, 4));
      const float ek = (k < 5) ? fexp(lk - mx) : 0.0f;
      float ss = ek + __shfl_xor(ek, 1);
      ss += __shfl_xor(ss, 2);
      ss += __shfl_xor(ss, 4);
      const float rss = frcp(ss);
      // gumbel argmax, first-max-wins
      float v = -INFINITY;
      if (k < 5) {
        float uv = u01f(pbits(g0, g1, (uint32_t)(row * 5 + k)));
        uv = fmaxf(TINYF, uv * (1.0f - TINYF) + TINYF);
        v = lk - flog(-flog(uv));
      }
      float vm = fmaxf(v, __shfl_xor(v, 1));
      vm = fmaxf(vm, __shfl_xor(vm, 2));
      vm = fmaxf(vm, __shfl_xor(vm, 4));
      int cand = (v == vm) ? k : 8;
      cand = min(cand, __shfl_xor(cand, 1));
      cand = min(cand, __shfl_xor(cand, 2));
      cand = min(cand, __shfl_xor(cand, 4));
      const int idx = cand;
      const size_t ob = head
          ? ((size_t)BN * TT * 30 + (size_t)(head - 1) * BN * TT * 15 + ((size_t)row * TT + t) * 15)
          : ((size_t)row * TT + t) * 30;
      if (k < 5) {
        out[ob + k] = ek * rss;
        out[ob + 5 + k] = psh[r * 80 + base + 5 + k];
        out[ob + 10 + k] = fexp(psh[r * 80 + base + 10 + k]);
        if (head == 0) {
          out[ob + 15 + k] = psh[r * 80 + 15 + k];
          out[ob + 20 + k] = fexp(psh[r * 80 + 20 + k]);
          out[ob + 25 + k] = ftanh(psh[r * 80 + 25 + k]);
        }
      }
      if (k == 0) {
        if (head == 0) {
          float uz0 = u01f(pbits(n0, n1, (uint32_t)(row * 2 + 0))) * 2.0f - LO_N;
          float uz1 = u01f(pbits(n0, n1, (uint32_t)(row * 2 + 1))) * 2.0f - LO_N;
          uz0 = fmaxf(-LO_N, uz0); uz1 = fmaxf(-LO_N, uz1);
          const float z0 = 1.41421356f * erfinv_f(uz0);
          const float z1 = 1.41421356f * erfinv_f(uz1);
          const float mu = psh[r * 80 + 5 + idx];
          const float sl = fexp(psh[r * 80 + 10 + idx]);
          const float mula = psh[r * 80 + 15 + idx];
          const float sla = fexp(psh[r * 80 + 20 + idx]);
          const float rho = ftanh(psh[r * 80 + 25 + idx]);
          conds[r * 8 + 0] = mu + sl * z0;
          conds[r * 8 + 1] = mula + sla * (rho * z0 + sqrtf(1.0f - rho * rho) * z1);
        } else {
          float uz = u01f(pbits(n0, n1, (uint32_t)row)) * 2.0f - LO_N;
          uz = fmaxf(-LO_N, uz);
          const float zz = 1.41421356f * erfinv_f(uz);
          conds[r * 8 + 1 + head] =
              psh[r * 80 + base + 5 + idx] + fexp(psh[r * 80 + base + 10 + idx]) * zz;
        }
      }
    }
    __syncthreads();
  }
}

extern "C" void kernel_launch(void* const* d_in, const int* in_sizes, int n_in,
                              void* d_out, int out_size, void* d_ws, size_t ws_size,
                              hipStream_t stream) {
  const float* conditions = (const float*)d_in[0];
  const float* state_h = (const float*)d_in[1];
  const float* state_c = (const float*)d_in[2];
  // d_in[3] = steps_n (=20, compile-time TT)
  const float* We1 = (const float*)d_in[4];
  const float* be1 = (const float*)d_in[5];
  const float* We2 = (const float*)d_in[6];
  const float* be2 = (const float*)d_in[7];
  const float* Wk  = (const float*)d_in[8];
  const float* Wr  = (const float*)d_in[9];
  const float* bl  = (const float*)d_in[10];
  const float* Wm  = (const float*)d_in[11];
  const float* bm  = (const float*)d_in[12];
  const float* Wy  = (const float*)d_in[13];
  const float* by  = (const float*)d_in[14];
  const float* Wf  = (const float*)d_in[15];
  const float* bf  = (const float*)d_in[16];
  const float* Wfa = (const float*)d_in[17];
  const float* bfa = (const float*)d_in[18];
  float* ws = (float*)d_ws;   // needs WS_END*4 ~= 1.24 MB
  float* out = (float*)d_out;

  prep_a<<<dim3(1111), dim3(256), 0, stream>>>(
      Wk, Wr, We1, be1, We2, be2, Wm, bm, Wy, by, Wf, bf, Wfa, bfa, ws);
  prep_b<<<dim3(4), dim3(256), 0, stream>>>(Wk, bl, ws);
  decode_main<<<dim3(BN / 8), dim3(512), 0, stream>>>(
      conditions, state_h, state_c, ws, out);
}

// Round 9
// 348.323 us; speedup vs baseline: 1.2628x; 1.1465x over previous
//
#include <hip/hip_runtime.h>
#include <stdint.h>
#include <math.h>

// Problem constants
#define BN 4096
#define TT 20
#define HH 256
#define EE 128
#define KK 5
#define NCOND 5

// ws layout (float indices)
#define WS_KEYS 0                       // 320 u32: per step, 4 heads x (k1.x,k1.y,k2.x,k2.y)
#define WS_TSC  512                     // 20*1024 cumulative ts@Wk[384:404]
#define WS_WTO  20992                   // 80*256 head weights [o][q] f32, o>=75 zero
#define WS_BIAS 41472                   // 80 concat head biases (pad 0)
#define WS_T1   41552                   // 5*128  We1@We2
#define WS_EB2  42192                   // 128    be1@We2 + be2
#define WS_ZC   42320                   // 1024   (be1@We2+be2)@Wk1 + bl
#define WS_M    43344                   // 5*1024 We1@We2@Wk1
#define WS_WSUM 48464                   // 256*1024  Wk[128:384] + Wr
#define WS_END  310608                  // 1.24 MB

#define TINYF 1.17549435e-38f
#define LO_N  0.99999994f               // -nextafter(-1,0)
#define LOG2E 1.44269504f
#define LN2   0.69314718f

// ---------------- Threefry-2x32 (JAX-exact) ----------------
__device__ __forceinline__ void tf2(uint32_t k0, uint32_t k1, uint32_t x0, uint32_t x1,
                                    uint32_t& o0, uint32_t& o1) {
  const uint32_t ks2 = k0 ^ k1 ^ 0x1BD11BDAu;
  x0 += k0; x1 += k1;
#define RND(r) { x0 += x1; x1 = (x1 << (r)) | (x1 >> (32 - (r))); x1 ^= x0; }
  RND(13) RND(15) RND(26) RND(6)   x0 += k1;  x1 += ks2 + 1u;
  RND(17) RND(29) RND(16) RND(24)  x0 += ks2; x1 += k0 + 2u;
  RND(13) RND(15) RND(26) RND(6)   x0 += k0;  x1 += k1 + 3u;
  RND(17) RND(29) RND(16) RND(24)  x0 += k1;  x1 += ks2 + 4u;
  RND(13) RND(15) RND(26) RND(6)   x0 += ks2; x1 += k0 + 5u;
#undef RND
  o0 = x0; o1 = x1;
}

// jax_threefry_partitionable: bits[n] = a ^ b, (a,b) = threefry2x32(key, (0, n))
__device__ __forceinline__ uint32_t pbits(uint32_t k0, uint32_t k1, uint32_t n) {
  uint32_t a, b;
  tf2(k0, k1, 0u, n, a, b);
  return a ^ b;
}

__device__ __forceinline__ float u01f(uint32_t bits) {
  return __uint_as_float((bits >> 9) | 0x3f800000u) - 1.0f;
}

// ---- hardware transcendentals (v_exp_f32 / v_log_f32 / v_rcp_f32) ----
__device__ __forceinline__ float fexp(float x) { return __builtin_amdgcn_exp2f(x * LOG2E); }
__device__ __forceinline__ float flog(float x) { return __builtin_amdgcn_logf(x) * LN2; }
__device__ __forceinline__ float frcp(float x) { return __builtin_amdgcn_rcpf(x); }
__device__ __forceinline__ float fsig(float x) {
  return frcp(1.0f + __builtin_amdgcn_exp2f(-x * LOG2E));
}
__device__ __forceinline__ float ftanh(float x) {
  return 1.0f - 2.0f * frcp(1.0f + __builtin_amdgcn_exp2f(x * (2.0f * LOG2E)));
}

// XLA ErfInv32 (Giles polynomial), log via hw
__device__ __forceinline__ float erfinv_f(float x) {
  float w = -flog(fmaf(-x, x, 1.0f));
  float p;
  if (w < 5.0f) {
    w = w - 2.5f;
    p = 2.81022636e-08f;
    p = 3.43273939e-07f + p * w;
    p = -3.5233877e-06f + p * w;
    p = -4.39150654e-06f + p * w;
    p = 0.00021858087f  + p * w;
    p = -0.00125372503f + p * w;
    p = -0.00417768164f + p * w;
    p = 0.246640727f    + p * w;
    p = 1.50140941f     + p * w;
  } else {
    w = sqrtf(w) - 3.0f;
    p = -0.000200214257f;
    p = 0.000100950558f + p * w;
    p = 0.00134934322f  + p * w;
    p = -0.00367342844f + p * w;
    p = 0.00573950773f  + p * w;
    p = -0.0076224613f  + p * w;
    p = 0.00943887047f  + p * w;
    p = 1.00167406f     + p * w;
    p = 2.83297682f     + p * w;
  }
  return p * x;
}

// ---------------- prep_a: keys, tsc, WTO/bias, T1/eb2, WSUM ----------------
__global__ __launch_bounds__(256) void prep_a(
    const float* __restrict__ Wk, const float* __restrict__ Wr,
    const float* __restrict__ We1, const float* __restrict__ be1,
    const float* __restrict__ We2, const float* __restrict__ be2,
    const float* __restrict__ Wm, const float* __restrict__ bm,
    const float* __restrict__ Wy, const float* __restrict__ by,
    const float* __restrict__ Wf, const float* __restrict__ bf,
    const float* __restrict__ Wfa, const float* __restrict__ bfa,
    float* __restrict__ ws) {
  const int bid = blockIdx.x, tid = threadIdx.x;
  if (bid == 0) {
    if (tid < 4) {
      uint32_t* keys = (uint32_t*)ws;
      const int l = tid;                 // 0=km 1=ky 2=kf 3=kfa
      uint32_t kx = 0u, ky = 42u;        // jax.random.key(42)
      for (int t = 0; t < TT; ++t) {
        uint32_t hx, hy;
        tf2(kx, ky, 0u, (uint32_t)(l + 1), hx, hy);
        uint32_t k1x, k1y, k2x, k2y;
        tf2(hx, hy, 0u, 0u, k1x, k1y);
        tf2(hx, hy, 0u, 1u, k2x, k2y);
        keys[t * 16 + l * 4 + 0] = k1x;
        keys[t * 16 + l * 4 + 1] = k1y;
        keys[t * 16 + l * 4 + 2] = k2x;
        keys[t * 16 + l * 4 + 3] = k2y;
        uint32_t nx, ny;
        tf2(kx, ky, 0u, 0u, nx, ny);
        kx = nx; ky = ny;
      }
    }
  } else if (bid <= 4) {
    const int col = (bid - 1) * 256 + tid;
    float s = 0.0f;
    for (int p = 0; p < TT; ++p) {
      s += Wk[(size_t)(EE + HH + p) * 1024 + col];
      ws[WS_TSC + p * 1024 + col] = s;
    }
  } else if (bid <= 84) {
    // WTO[o][q] f32 head weights, rows o>=75 zero
    const int idx = (bid - 5) * 256 + tid;   // < 20480
    const int o = idx >> 8, q = idx & 255;
    float v = 0.0f;
    if (o < 30)      v = Wm[q * 30 + o];
    else if (o < 45) v = Wy[q * 15 + (o - 30)];
    else if (o < 60) v = Wf[q * 15 + (o - 45)];
    else if (o < 75) v = Wfa[q * 15 + (o - 60)];
    ws[WS_WTO + idx] = v;
  } else if (bid == 85) {
    if (tid < 80) {
      float v = 0.0f;
      if (tid < 30)      v = bm[tid];
      else if (tid < 45) v = by[tid - 30];
      else if (tid < 60) v = bf[tid - 45];
      else if (tid < 75) v = bfa[tid - 60];
      ws[WS_BIAS + tid] = v;
    }
  } else if (bid == 86) {
    // T1[c][q] = sum_e We1[c][e]*We2[e][q]; eb2[q] = be2[q] + sum_e be1[e]*We2[e][q]
    if (tid < EE) {
      const int q = tid;
      float t0 = 0.f, t1 = 0.f, t2 = 0.f, t3 = 0.f, t4 = 0.f;
      float eb = be2[q];
      for (int e = 0; e < EE; ++e) {
        const float w2 = We2[e * EE + q];
        t0 = fmaf(We1[0 * EE + e], w2, t0);
        t1 = fmaf(We1[1 * EE + e], w2, t1);
        t2 = fmaf(We1[2 * EE + e], w2, t2);
        t3 = fmaf(We1[3 * EE + e], w2, t3);
        t4 = fmaf(We1[4 * EE + e], w2, t4);
        eb = fmaf(be1[e], w2, eb);
      }
      ws[WS_T1 + 0 * EE + q] = t0;
      ws[WS_T1 + 1 * EE + q] = t1;
      ws[WS_T1 + 2 * EE + q] = t2;
      ws[WS_T1 + 3 * EE + q] = t3;
      ws[WS_T1 + 4 * EE + q] = t4;
      ws[WS_EB2 + q] = eb;
    }
  } else {
    // WSUM[q][col] = Wk[128+q][col] + Wr[q][col]
    const int idx = (bid - 87) * 256 + tid;
    if (idx < 256 * 1024) {
      const int q = idx >> 10, col = idx & 1023;
      ws[WS_WSUM + idx] = Wk[(size_t)(EE + q) * 1024 + col] + Wr[(size_t)q * 1024 + col];
    }
  }
}

// ---------------- prep_b: M = T1@Wk1 (5x1024), zc = eb2@Wk1 + bl ----------------
__global__ __launch_bounds__(256) void prep_b(
    const float* __restrict__ Wk, const float* __restrict__ bl,
    float* __restrict__ ws) {
  const int col = blockIdx.x * 256 + threadIdx.x;   // 0..1023
  float m0 = 0.f, m1 = 0.f, m2 = 0.f, m3 = 0.f, m4 = 0.f;
  float zacc = bl[col];
  for (int q = 0; q < EE; ++q) {
    const float wv = Wk[(size_t)q * 1024 + col];
    m0 = fmaf(ws[WS_T1 + 0 * EE + q], wv, m0);
    m1 = fmaf(ws[WS_T1 + 1 * EE + q], wv, m1);
    m2 = fmaf(ws[WS_T1 + 2 * EE + q], wv, m2);
    m3 = fmaf(ws[WS_T1 + 3 * EE + q], wv, m3);
    m4 = fmaf(ws[WS_T1 + 4 * EE + q], wv, m4);
    zacc = fmaf(ws[WS_EB2 + q], wv, zacc);
  }
  ws[WS_M + 0 * 1024 + col] = m0;
  ws[WS_M + 1 * 1024 + col] = m1;
  ws[WS_M + 2 * 1024 + col] = m2;
  ws[WS_M + 3 * 1024 + col] = m3;
  ws[WS_M + 4 * 1024 + col] = m4;
  ws[WS_ZC + col] = zacc;
}

// ---------------- main: 8 rows/block, 512 blocks, 20 steps ----------------
// Phase A: thread (u = tid&255, half = tid>>8) -> 4 rows x unit u.
// Phase B: wave ch = tid>>6 owns q-chunk [32ch,+32); lane pr = tid&63 (pr<38)
//          owns outputs {2pr,2pr+1}; weights re-loaded from L1/L2 each step
//          (loop-local liveness -> no spill; 64B-line reuse across j4).
// Phase C: tid<256: lane = (row r, head, k) with 8-lane shfl groups.
__global__ __launch_bounds__(512) void decode_main(
    const float* __restrict__ conditions, const float* __restrict__ state_h,
    const float* __restrict__ state_c, const float* __restrict__ ws,
    float* __restrict__ out) {
  __shared__ float Msh[5 * 1024];       // 20 KB
  __shared__ float hsh[8 * HH];         // 8 KB: state_h staging -> h
  __shared__ float pp[8][8][80];        // 20 KB head partials per q-chunk
  __shared__ float psh[8 * 80];         // 2.5 KB head outputs
  __shared__ float biasL[80];
  __shared__ float conds[8 * 8];
  __shared__ uint32_t keysL[TT * 16];

  const int tid = threadIdx.x;
  const int row0 = blockIdx.x * 8;
  const int u = tid & 255;
  const int half = tid >> 8;
  const int rbase = half * 4;

  // ---- prologue staging ----
  for (int i = tid; i < 5 * 1024; i += 512) Msh[i] = ws[WS_M + i];
  if (tid < 80) biasL[tid] = ws[WS_BIAS + tid];
  for (int i = tid; i < TT * 16; i += 512) keysL[i] = ((const uint32_t*)ws)[WS_KEYS + i];
  if (tid < 8 * NCOND) {
    const int r = tid / NCOND, c = tid - r * NCOND;
    conds[r * 8 + c] = conditions[(size_t)(row0 + r) * (TT * NCOND) + c];  // [:,0,:]
  }
  for (int i = tid; i < 8 * HH; i += 512) hsh[i] = state_h[(size_t)row0 * HH + i];

  // Phase-B role constants
  const int ch = tid >> 6;              // q-chunk 0..7 (uniform per wave)
  const int pr = tid & 63;              // output pair
  const bool bact = (pr < 38);
  const int oA = bact ? 2 * pr : 76;    // clamped to zero-pad rows for inactive lanes
  const int oB = oA + 1;
  const float4* wA4 = (const float4*)&ws[WS_WTO + oA * 256 + ch * 32];
  const float4* wB4 = (const float4*)&ws[WS_WTO + oB * 256 + ch * 32];

  float sc[4];
#pragma unroll
  for (int rr = 0; rr < 4; ++rr) sc[rr] = state_c[(size_t)(row0 + rbase + rr) * HH + u];
  __syncthreads();

  // ---- step-invariant cz[gate][row] = zc + state_h @ WSUM (exact fp32) ----
  float cz[4][4];
#pragma unroll
  for (int g = 0; g < 4; ++g) {
    const float z = ws[WS_ZC + g * 256 + u];
#pragma unroll
    for (int rr = 0; rr < 4; ++rr) cz[g][rr] = z;
  }
  for (int q = 0; q < HH; ++q) {
    const float w0 = ws[WS_WSUM + q * 1024 + u];
    const float w1 = ws[WS_WSUM + q * 1024 + 256 + u];
    const float w2 = ws[WS_WSUM + q * 1024 + 512 + u];
    const float w3 = ws[WS_WSUM + q * 1024 + 768 + u];
#pragma unroll
    for (int rr = 0; rr < 4; ++rr) {
      const float e = hsh[(rbase + rr) * HH + q];
      cz[0][rr] = fmaf(e, w0, cz[0][rr]);
      cz[1][rr] = fmaf(e, w1, cz[1][rr]);
      cz[2][rr] = fmaf(e, w2, cz[2][rr]);
      cz[3][rr] = fmaf(e, w3, cz[3][rr]);
    }
  }
  __syncthreads();   // hsh(state_h) dead -> h buffer

  for (int t = 0; t < TT; ++t) {
    // ---- Phase A: z = cond@M + cz + tsc[t]; gates -> h -> hsh ----
    {
      const float ts0 = ws[WS_TSC + t * 1024 + u];
      const float ts1 = ws[WS_TSC + t * 1024 + 256 + u];
      const float ts2 = ws[WS_TSC + t * 1024 + 512 + u];
      const float ts3 = ws[WS_TSC + t * 1024 + 768 + u];
      float mA[5], mB[5], mC[5], mD[5];
#pragma unroll
      for (int c = 0; c < 5; ++c) {
        mA[c] = Msh[c * 1024 + u];
        mB[c] = Msh[c * 1024 + 256 + u];
        mC[c] = Msh[c * 1024 + 512 + u];
        mD[c] = Msh[c * 1024 + 768 + u];
      }
#pragma unroll
      for (int rr = 0; rr < 4; ++rr) {
        const int row = rbase + rr;
        const float c0 = conds[row * 8 + 0], c1 = conds[row * 8 + 1], c2 = conds[row * 8 + 2],
                    c3 = conds[row * 8 + 3], c4 = conds[row * 8 + 4];
        float zi = cz[0][rr] + ts0, zf = cz[1][rr] + ts1,
              zg = cz[2][rr] + ts2, zo = cz[3][rr] + ts3;
        zi = fmaf(c0, mA[0], zi); zi = fmaf(c1, mA[1], zi); zi = fmaf(c2, mA[2], zi);
        zi = fmaf(c3, mA[3], zi); zi = fmaf(c4, mA[4], zi);
        zf = fmaf(c0, mB[0], zf); zf = fmaf(c1, mB[1], zf); zf = fmaf(c2, mB[2], zf);
        zf = fmaf(c3, mB[3], zf); zf = fmaf(c4, mB[4], zf);
        zg = fmaf(c0, mC[0], zg); zg = fmaf(c1, mC[1], zg); zg = fmaf(c2, mC[2], zg);
        zg = fmaf(c3, mC[3], zg); zg = fmaf(c4, mC[4], zg);
        zo = fmaf(c0, mD[0], zo); zo = fmaf(c1, mD[1], zo); zo = fmaf(c2, mD[2], zo);
        zo = fmaf(c3, mD[3], zo); zo = fmaf(c4, mD[4], zo);
        const float cv = fsig(zf) * sc[rr] + fsig(zi) * ftanh(zg);
        const float hv = fsig(zo) * ftanh(cv);
        hsh[row * HH + u] = hv;
      }
    }
    __syncthreads();
    // ---- Phase B: 2 outputs x 32-q chunk; weights streamed from L1/L2 ----
    {
      float a0[8], a1[8];
#pragma unroll
      for (int r = 0; r < 8; ++r) { a0[r] = 0.0f; a1[r] = 0.0f; }
      const float4* h4 = (const float4*)hsh;
#pragma unroll
      for (int j4 = 0; j4 < 8; ++j4) {
        const float4 wa = wA4[j4];
        const float4 wb = wB4[j4];
#pragma unroll
        for (int r = 0; r < 8; ++r) {
          const float4 hv = h4[r * 64 + ch * 8 + j4];
          a0[r] = fmaf(hv.x, wa.x, a0[r]);
          a0[r] = fmaf(hv.y, wa.y, a0[r]);
          a0[r] = fmaf(hv.z, wa.z, a0[r]);
          a0[r] = fmaf(hv.w, wa.w, a0[r]);
          a1[r] = fmaf(hv.x, wb.x, a1[r]);
          a1[r] = fmaf(hv.y, wb.y, a1[r]);
          a1[r] = fmaf(hv.z, wb.z, a1[r]);
          a1[r] = fmaf(hv.w, wb.w, a1[r]);
        }
      }
      if (bact) {
#pragma unroll
        for (int r = 0; r < 8; ++r) {
          *(float2*)&pp[ch][r][2 * pr] = make_float2(a0[r], a1[r]);
        }
      }
    }
    __syncthreads();
    // ---- reduce partials: psh[r][o] = bias + sum_ch pp ----
    for (int s = tid; s < 640; s += 512) {
      const int rr = s / 80, o = s - rr * 80;
      if (o < 76) {
        float acc = biasL[o];
#pragma unroll
        for (int c = 0; c < 8; ++c) acc += pp[c][rr][o];
        psh[rr * 80 + o] = acc;
      }
    }
    __syncthreads();
    // ---- Phase C: wave-parallel sampling; lane = (r, head, k) ----
    if (tid < 256) {
      const int g8 = tid >> 3, k = tid & 7;
      const int r = g8 >> 2, head = g8 & 3;
      const int row = row0 + r;
      const int base = head ? (30 + 15 * (head - 1)) : 0;
      const uint32_t g0 = keysL[t * 16 + head * 4 + 0], g1 = keysL[t * 16 + head * 4 + 1];
      const uint32_t n0 = keysL[t * 16 + head * 4 + 2], n1 = keysL[t * 16 + head * 4 + 3];
      const float lk = (k < 5) ? psh[r * 80 + base + k] : -INFINITY;
      float mx = fmaxf(lk, __shfl_xor(lk, 1));
      mx = fmaxf(mx, __shfl_xor(mx, 2));
      mx = fmaxf(mx, __shfl_xor(mx, 4));
      const float ek = (k < 5) ? fexp(lk - mx) : 0.0f;
      float ss = ek + __shfl_xor(ek, 1);
      ss += __shfl_xor(ss, 2);
      ss += __shfl_xor(ss, 4);
      const float rss = frcp(ss);
      // gumbel argmax, first-max-wins
      float v = -INFINITY;
      if (k < 5) {
        float uv = u01f(pbits(g0, g1, (uint32_t)(row * 5 + k)));
        uv = fmaxf(TINYF, uv * (1.0f - TINYF) + TINYF);
        v = lk - flog(-flog(uv));
      }
      float vm = fmaxf(v, __shfl_xor(v, 1));
      vm = fmaxf(vm, __shfl_xor(vm, 2));
      vm = fmaxf(vm, __shfl_xor(vm, 4));
      int cand = (v == vm) ? k : 8;
      cand = min(cand, __shfl_xor(cand, 1));
      cand = min(cand, __shfl_xor(cand, 2));
      cand = min(cand, __shfl_xor(cand, 4));
      const int idx = cand;
      const size_t ob = head
          ? ((size_t)BN * TT * 30 + (size_t)(head - 1) * BN * TT * 15 + ((size_t)row * TT + t) * 15)
          : ((size_t)row * TT + t) * 30;
      if (k < 5) {
        out[ob + k] = ek * rss;
        out[ob + 5 + k] = psh[r * 80 + base + 5 + k];
        out[ob + 10 + k] = fexp(psh[r * 80 + base + 10 + k]);
        if (head == 0) {
          out[ob + 15 + k] = psh[r * 80 + 15 + k];
          out[ob + 20 + k] = fexp(psh[r * 80 + 20 + k]);
          out[ob + 25 + k] = ftanh(psh[r * 80 + 25 + k]);
        }
      }
      if (k == 0) {
        if (head == 0) {
          float uz0 = u01f(pbits(n0, n1, (uint32_t)(row * 2 + 0))) * 2.0f - LO_N;
          float uz1 = u01f(pbits(n0, n1, (uint32_t)(row * 2 + 1))) * 2.0f - LO_N;
          uz0 = fmaxf(-LO_N, uz0); uz1 = fmaxf(-LO_N, uz1);
          const float z0 = 1.41421356f * erfinv_f(uz0);
          const float z1 = 1.41421356f * erfinv_f(uz1);
          const float mu = psh[r * 80 + 5 + idx];
          const float sl = fexp(psh[r * 80 + 10 + idx]);
          const float mula = psh[r * 80 + 15 + idx];
          const float sla = fexp(psh[r * 80 + 20 + idx]);
          const float rho = ftanh(psh[r * 80 + 25 + idx]);
          conds[r * 8 + 0] = mu + sl * z0;
          conds[r * 8 + 1] = mula + sla * (rho * z0 + sqrtf(1.0f - rho * rho) * z1);
        } else {
          float uz = u01f(pbits(n0, n1, (uint32_t)row)) * 2.0f - LO_N;
          uz = fmaxf(-LO_N, uz);
          const float zz = 1.41421356f * erfinv_f(uz);
          conds[r * 8 + 1 + head] =
              psh[r * 80 + base + 5 + idx] + fexp(psh[r * 80 + base + 10 + idx]) * zz;
        }
      }
    }
    __syncthreads();
  }
}

extern "C" void kernel_launch(void* const* d_in, const int* in_sizes, int n_in,
                              void* d_out, int out_size, void* d_ws, size_t ws_size,
                              hipStream_t stream) {
  const float* conditions = (const float*)d_in[0];
  const float* state_h = (const float*)d_in[1];
  const float* state_c = (const float*)d_in[2];
  // d_in[3] = steps_n (=20, compile-time TT)
  const float* We1 = (const float*)d_in[4];
  const float* be1 = (const float*)d_in[5];
  const float* We2 = (const float*)d_in[6];
  const float* be2 = (const float*)d_in[7];
  const float* Wk  = (const float*)d_in[8];
  const float* Wr  = (const float*)d_in[9];
  const float* bl  = (const float*)d_in[10];
  const float* Wm  = (const float*)d_in[11];
  const float* bm  = (const float*)d_in[12];
  const float* Wy  = (const float*)d_in[13];
  const float* by  = (const float*)d_in[14];
  const float* Wf  = (const float*)d_in[15];
  const float* bf  = (const float*)d_in[16];
  const float* Wfa = (const float*)d_in[17];
  const float* bfa = (const float*)d_in[18];
  float* ws = (float*)d_ws;   // needs WS_END*4 ~= 1.24 MB
  float* out = (float*)d_out;

  prep_a<<<dim3(1111), dim3(256), 0, stream>>>(
      Wk, Wr, We1, be1, We2, be2, Wm, bm, Wy, by, Wf, bf, Wfa, bfa, ws);
  prep_b<<<dim3(4), dim3(256), 0, stream>>>(Wk, bl, ws);
  decode_main<<<dim3(BN / 8), dim3(512), 0, stream>>>(
      conditions, state_h, state_c, ws, out);
}

// Round 11
// 172.843 us; speedup vs baseline: 2.5449x; 2.0153x over previous
//
#include <hip/hip_runtime.h>
#include <stdint.h>
#include <math.h>

// Problem constants
#define BN 4096
#define TT 20
#define HH 256
#define EE 128
#define KK 5
#define NCOND 5

// ws layout (float indices)
#define WS_KEYS 0                       // 320 u32: per step, 4 heads x (k1.x,k1.y,k2.x,k2.y)
#define WS_TSC  512                     // 20*1024 cumulative ts@Wk[384:404]
#define WS_WTB  20992                   // 80*256 bf16 u16, swizzled [n][k^((n&7)<<3)]
#define WS_BIAS 41472                   // 80 concat head biases (pad 0)
#define WS_T1   41552                   // 5*128  We1@We2
#define WS_EB2  42192                   // 128    be1@We2 + be2
#define WS_ZC   42320                   // 1024   (be1@We2+be2)@Wk1 + bl
#define WS_M    43344                   // 5*1024 We1@We2@Wk1
#define WS_WSUM 48464                   // 256*1024  Wk[128:384] + Wr
#define WS_END  310608                  // 1.24 MB

#define TINYF 1.17549435e-38f
#define LO_N  0.99999994f               // -nextafter(-1,0)
#define LOG2E 1.44269504f
#define LN2   0.69314718f

typedef __attribute__((ext_vector_type(8))) short short8v;   // 8 bf16 (4 VGPRs)
typedef __attribute__((ext_vector_type(4))) float f32x4;     // 4 fp32 acc

// ---------------- Threefry-2x32 (JAX-exact) ----------------
__device__ __forceinline__ void tf2(uint32_t k0, uint32_t k1, uint32_t x0, uint32_t x1,
                                    uint32_t& o0, uint32_t& o1) {
  const uint32_t ks2 = k0 ^ k1 ^ 0x1BD11BDAu;
  x0 += k0; x1 += k1;
#define RND(r) { x0 += x1; x1 = (x1 << (r)) | (x1 >> (32 - (r))); x1 ^= x0; }
  RND(13) RND(15) RND(26) RND(6)   x0 += k1;  x1 += ks2 + 1u;
  RND(17) RND(29) RND(16) RND(24)  x0 += ks2; x1 += k0 + 2u;
  RND(13) RND(15) RND(26) RND(6)   x0 += k0;  x1 += k1 + 3u;
  RND(17) RND(29) RND(16) RND(24)  x0 += k1;  x1 += ks2 + 4u;
  RND(13) RND(15) RND(26) RND(6)   x0 += ks2; x1 += k0 + 5u;
#undef RND
  o0 = x0; o1 = x1;
}

// jax_threefry_partitionable: bits[n] = a ^ b, (a,b) = threefry2x32(key, (0, n))
__device__ __forceinline__ uint32_t pbits(uint32_t k0, uint32_t k1, uint32_t n) {
  uint32_t a, b;
  tf2(k0, k1, 0u, n, a, b);
  return a ^ b;
}

__device__ __forceinline__ float u01f(uint32_t bits) {
  return __uint_as_float((bits >> 9) | 0x3f800000u) - 1.0f;
}

// ---- hardware transcendentals (v_exp_f32 / v_log_f32 / v_rcp_f32) ----
__device__ __forceinline__ float fexp(float x) { return __builtin_amdgcn_exp2f(x * LOG2E); }
__device__ __forceinline__ float flog(float x) { return __builtin_amdgcn_logf(x) * LN2; }
__device__ __forceinline__ float frcp(float x) { return __builtin_amdgcn_rcpf(x); }
__device__ __forceinline__ float fsig(float x) {
  return frcp(1.0f + __builtin_amdgcn_exp2f(-x * LOG2E));
}
__device__ __forceinline__ float ftanh(float x) {
  return 1.0f - 2.0f * frcp(1.0f + __builtin_amdgcn_exp2f(x * (2.0f * LOG2E)));
}

// XLA ErfInv32 (Giles polynomial), log via hw
__device__ __forceinline__ float erfinv_f(float x) {
  float w = -flog(fmaf(-x, x, 1.0f));
  float p;
  if (w < 5.0f) {
    w = w - 2.5f;
    p = 2.81022636e-08f;
    p = 3.43273939e-07f + p * w;
    p = -3.5233877e-06f + p * w;
    p = -4.39150654e-06f + p * w;
    p = 0.00021858087f  + p * w;
    p = -0.00125372503f + p * w;
    p = -0.00417768164f + p * w;
    p = 0.246640727f    + p * w;
    p = 1.50140941f     + p * w;
  } else {
    w = sqrtf(w) - 3.0f;
    p = -0.000200214257f;
    p = 0.000100950558f + p * w;
    p = 0.00134934322f  + p * w;
    p = -0.00367342844f + p * w;
    p = 0.00573950773f  + p * w;
    p = -0.0076224613f  + p * w;
    p = 0.00943887047f  + p * w;
    p = 1.00167406f     + p * w;
    p = 2.83297682f     + p * w;
  }
  return p * x;
}

// round-to-nearest-even f32 -> bf16 bits
__device__ __forceinline__ uint32_t bf16rne(float f) {
  uint32_t u = __float_as_uint(f);
  return (u + 0x7fffu + ((u >> 16) & 1u)) >> 16;
}

// ---------------- prep_a: keys, tsc, WTB(bf16 swizzled)/bias, T1/eb2, WSUM --------
__global__ __launch_bounds__(256) void prep_a(
    const float* __restrict__ Wk, const float* __restrict__ Wr,
    const float* __restrict__ We1, const float* __restrict__ be1,
    const float* __restrict__ We2, const float* __restrict__ be2,
    const float* __restrict__ Wm, const float* __restrict__ bm,
    const float* __restrict__ Wy, const float* __restrict__ by,
    const float* __restrict__ Wf, const float* __restrict__ bf,
    const float* __restrict__ Wfa, const float* __restrict__ bfa,
    float* __restrict__ ws) {
  const int bid = blockIdx.x, tid = threadIdx.x;
  if (bid == 0) {
    if (tid < 4) {
      uint32_t* keys = (uint32_t*)ws;
      const int l = tid;                 // 0=km 1=ky 2=kf 3=kfa
      uint32_t kx = 0u, ky = 42u;        // jax.random.key(42)
      for (int t = 0; t < TT; ++t) {
        uint32_t hx, hy;
        tf2(kx, ky, 0u, (uint32_t)(l + 1), hx, hy);
        uint32_t k1x, k1y, k2x, k2y;
        tf2(hx, hy, 0u, 0u, k1x, k1y);
        tf2(hx, hy, 0u, 1u, k2x, k2y);
        keys[t * 16 + l * 4 + 0] = k1x;
        keys[t * 16 + l * 4 + 1] = k1y;
        keys[t * 16 + l * 4 + 2] = k2x;
        keys[t * 16 + l * 4 + 3] = k2y;
        uint32_t nx, ny;
        tf2(kx, ky, 0u, 0u, nx, ny);
        kx = nx; ky = ny;
      }
    }
  } else if (bid <= 4) {
    const int col = (bid - 1) * 256 + tid;
    float s = 0.0f;
    for (int p = 0; p < TT; ++p) {
      s += Wk[(size_t)(EE + HH + p) * 1024 + col];
      ws[WS_TSC + p * 1024 + col] = s;
    }
  } else if (bid <= 84) {
    // WTB: bf16 head weights [n][k], swizzled k' = k ^ ((n&7)<<3); rows n>=75 zero
    const int idx = (bid - 5) * 256 + tid;   // < 20480
    const int o = idx >> 8, q = idx & 255;
    float v = 0.0f;
    if (o < 30)      v = Wm[q * 30 + o];
    else if (o < 45) v = Wy[q * 15 + (o - 30)];
    else if (o < 60) v = Wf[q * 15 + (o - 45)];
    else if (o < 75) v = Wfa[q * 15 + (o - 60)];
    uint16_t* wtb = (uint16_t*)&ws[WS_WTB];
    wtb[o * 256 + (q ^ ((o & 7) << 3))] = (uint16_t)bf16rne(v);
  } else if (bid == 85) {
    if (tid < 80) {
      float v = 0.0f;
      if (tid < 30)      v = bm[tid];
      else if (tid < 45) v = by[tid - 30];
      else if (tid < 60) v = bf[tid - 45];
      else if (tid < 75) v = bfa[tid - 60];
      ws[WS_BIAS + tid] = v;
    }
  } else if (bid == 86) {
    // T1[c][q] = sum_e We1[c][e]*We2[e][q]; eb2[q] = be2[q] + sum_e be1[e]*We2[e][q]
    if (tid < EE) {
      const int q = tid;
      float t0 = 0.f, t1 = 0.f, t2 = 0.f, t3 = 0.f, t4 = 0.f;
      float eb = be2[q];
      for (int e = 0; e < EE; ++e) {
        const float w2 = We2[e * EE + q];
        t0 = fmaf(We1[0 * EE + e], w2, t0);
        t1 = fmaf(We1[1 * EE + e], w2, t1);
        t2 = fmaf(We1[2 * EE + e], w2, t2);
        t3 = fmaf(We1[3 * EE + e], w2, t3);
        t4 = fmaf(We1[4 * EE + e], w2, t4);
        eb = fmaf(be1[e], w2, eb);
      }
      ws[WS_T1 + 0 * EE + q] = t0;
      ws[WS_T1 + 1 * EE + q] = t1;
      ws[WS_T1 + 2 * EE + q] = t2;
      ws[WS_T1 + 3 * EE + q] = t3;
      ws[WS_T1 + 4 * EE + q] = t4;
      ws[WS_EB2 + q] = eb;
    }
  } else {
    // WSUM[q][col] = Wk[128+q][col] + Wr[q][col]
    const int idx = (bid - 87) * 256 + tid;
    if (idx < 256 * 1024) {
      const int q = idx >> 10, col = idx & 1023;
      ws[WS_WSUM + idx] = Wk[(size_t)(EE + q) * 1024 + col] + Wr[(size_t)q * 1024 + col];
    }
  }
}

// ---------------- prep_b: M = T1@Wk1 (5x1024), zc = eb2@Wk1 + bl ----------------
__global__ __launch_bounds__(256) void prep_b(
    const float* __restrict__ Wk, const float* __restrict__ bl,
    float* __restrict__ ws) {
  const int col = blockIdx.x * 256 + threadIdx.x;   // 0..1023
  float m0 = 0.f, m1 = 0.f, m2 = 0.f, m3 = 0.f, m4 = 0.f;
  float zacc = bl[col];
  for (int q = 0; q < EE; ++q) {
    const float wv = Wk[(size_t)q * 1024 + col];
    m0 = fmaf(ws[WS_T1 + 0 * EE + q], wv, m0);
    m1 = fmaf(ws[WS_T1 + 1 * EE + q], wv, m1);
    m2 = fmaf(ws[WS_T1 + 2 * EE + q], wv, m2);
    m3 = fmaf(ws[WS_T1 + 3 * EE + q], wv, m3);
    m4 = fmaf(ws[WS_T1 + 4 * EE + q], wv, m4);
    zacc = fmaf(ws[WS_EB2 + q], wv, zacc);
  }
  ws[WS_M + 0 * 1024 + col] = m0;
  ws[WS_M + 1 * 1024 + col] = m1;
  ws[WS_M + 2 * 1024 + col] = m2;
  ws[WS_M + 3 * 1024 + col] = m3;
  ws[WS_M + 4 * 1024 + col] = m4;
  ws[WS_ZC + col] = zacc;
}

// ---------------- main: 8 rows/block, 512 blocks, 20 steps ----------------
// Phase A: thread (u = tid&255, half = tid>>8) -> 4 rows x unit u; h -> bf16 LDS.
// Phase B: MFMA 16x16x32_bf16: waves 0..4 each own one 16-col output tile;
//          K=256 = 8 accumulating mfma; psh written pre-biased from C/D frag.
// Phase C: tid<256: lane = (row r, head, k) with 8-lane shfl groups.
__global__ __launch_bounds__(512) void decode_main(
    const float* __restrict__ conditions, const float* __restrict__ state_h,
    const float* __restrict__ state_c, const float* __restrict__ ws,
    float* __restrict__ out) {
  __shared__ float Msh[5 * 1024];       // 20 KB
  __shared__ short WTBs[80 * 256];      // 40 KB bf16 swizzled weights [n][k^((n&7)<<3)]
  __shared__ short hb[16 * 256];        // 8 KB bf16 swizzled h (rows 8..15 zero)
  __shared__ float psh[8 * 80];         // 2.5 KB head outputs (pre-biased)
  __shared__ float biasL[80];
  __shared__ float conds[8 * 8];
  __shared__ uint32_t keysL[TT * 16];

  const int tid = threadIdx.x;
  const int row0 = blockIdx.x * 8;
  const int u = tid & 255;
  const int half = tid >> 8;
  const int rbase = half * 4;

  // ---- prologue part 1: state_h f32 staged into WTBs area (alias, pre-weights) ----
  float* hstage = (float*)WTBs;         // 8*256 f32 = 8 KB of the 40 KB region
  for (int i = tid; i < 8 * HH; i += 512) hstage[i] = state_h[(size_t)row0 * HH + i];
  for (int i = tid; i < 5 * 1024; i += 512) Msh[i] = ws[WS_M + i];
  if (tid < 80) biasL[tid] = ws[WS_BIAS + tid];
  for (int i = tid; i < TT * 16; i += 512) keysL[i] = ((const uint32_t*)ws)[WS_KEYS + i];
  if (tid < 8 * NCOND) {
    const int r = tid / NCOND, c = tid - r * NCOND;
    conds[r * 8 + c] = conditions[(size_t)(row0 + r) * (TT * NCOND) + c];  // [:,0,:]
  }
  float sc[4];
#pragma unroll
  for (int rr = 0; rr < 4; ++rr) sc[rr] = state_c[(size_t)(row0 + rbase + rr) * HH + u];
  __syncthreads();

  // ---- step-invariant cz[gate][row] = zc + state_h @ WSUM (exact fp32) ----
  float cz[4][4];
#pragma unroll
  for (int g = 0; g < 4; ++g) {
    const float z = ws[WS_ZC + g * 256 + u];
#pragma unroll
    for (int rr = 0; rr < 4; ++rr) cz[g][rr] = z;
  }
  for (int q = 0; q < HH; ++q) {
    const float w0 = ws[WS_WSUM + q * 1024 + u];
    const float w1 = ws[WS_WSUM + q * 1024 + 256 + u];
    const float w2 = ws[WS_WSUM + q * 1024 + 512 + u];
    const float w3 = ws[WS_WSUM + q * 1024 + 768 + u];
#pragma unroll
    for (int rr = 0; rr < 4; ++rr) {
      const float e = hstage[(rbase + rr) * HH + q];
      cz[0][rr] = fmaf(e, w0, cz[0][rr]);
      cz[1][rr] = fmaf(e, w1, cz[1][rr]);
      cz[2][rr] = fmaf(e, w2, cz[2][rr]);
      cz[3][rr] = fmaf(e, w3, cz[3][rr]);
    }
  }
  __syncthreads();   // hstage dead -> load weights over it

  // ---- prologue part 2: stage bf16 weights; zero hb pad rows (words 1024..2047) ----
  {
    uint32_t* dst = (uint32_t*)WTBs;
    const uint32_t* src = (const uint32_t*)&ws[WS_WTB];
    for (int i = tid; i < 80 * 128; i += 512) dst[i] = src[i];
    uint32_t* hz = (uint32_t*)hb;
    for (int i = tid; i < 1024; i += 512) hz[1024 + i] = 0u;   // rows 8..15 ONLY
  }
  __syncthreads();

  for (int t = 0; t < TT; ++t) {
    // ---- Phase A: z = cond@M + cz + tsc[t]; gates -> h -> hb (bf16, swizzled) ----
    {
      const float ts0 = ws[WS_TSC + t * 1024 + u];
      const float ts1 = ws[WS_TSC + t * 1024 + 256 + u];
      const float ts2 = ws[WS_TSC + t * 1024 + 512 + u];
      const float ts3 = ws[WS_TSC + t * 1024 + 768 + u];
      float mA[5], mB[5], mC[5], mD[5];
#pragma unroll
      for (int c = 0; c < 5; ++c) {
        mA[c] = Msh[c * 1024 + u];
        mB[c] = Msh[c * 1024 + 256 + u];
        mC[c] = Msh[c * 1024 + 512 + u];
        mD[c] = Msh[c * 1024 + 768 + u];
      }
#pragma unroll
      for (int rr = 0; rr < 4; ++rr) {
        const int row = rbase + rr;
        const float c0 = conds[row * 8 + 0], c1 = conds[row * 8 + 1], c2 = conds[row * 8 + 2],
                    c3 = conds[row * 8 + 3], c4 = conds[row * 8 + 4];
        float zi = cz[0][rr] + ts0, zf = cz[1][rr] + ts1,
              zg = cz[2][rr] + ts2, zo = cz[3][rr] + ts3;
        zi = fmaf(c0, mA[0], zi); zi = fmaf(c1, mA[1], zi); zi = fmaf(c2, mA[2], zi);
        zi = fmaf(c3, mA[3], zi); zi = fmaf(c4, mA[4], zi);
        zf = fmaf(c0, mB[0], zf); zf = fmaf(c1, mB[1], zf); zf = fmaf(c2, mB[2], zf);
        zf = fmaf(c3, mB[3], zf); zf = fmaf(c4, mB[4], zf);
        zg = fmaf(c0, mC[0], zg); zg = fmaf(c1, mC[1], zg); zg = fmaf(c2, mC[2], zg);
        zg = fmaf(c3, mC[3], zg); zg = fmaf(c4, mC[4], zg);
        zo = fmaf(c0, mD[0], zo); zo = fmaf(c1, mD[1], zo); zo = fmaf(c2, mD[2], zo);
        zo = fmaf(c3, mD[3], zo); zo = fmaf(c4, mD[4], zo);
        const float cv = fsig(zf) * sc[rr] + fsig(zi) * ftanh(zg);
        const float hv = fsig(zo) * ftanh(cv);
        hb[row * 256 + (u ^ ((row & 7) << 3))] = (short)bf16rne(hv);
      }
    }
    __syncthreads();
    // ---- Phase B: MFMA heads. waves 0..4: tile n0 = wv, K=256 via 8 mfma ----
    {
      const int wv = tid >> 6;
      if (wv < 5) {
        const int lane = tid & 63;
        const int rc = lane & 15;        // A row (m) and B col-in-tile
        const int hq = lane >> 4;        // 0..3 k-subgroup
        const int nn = wv * 16 + rc;     // output index / WTBs row
        const int aswz = (rc & 7) << 3;
        const int bswz = (nn & 7) << 3;
        f32x4 acc = {0.0f, 0.0f, 0.0f, 0.0f};
#pragma unroll
        for (int kk = 0; kk < 8; ++kk) {
          const int kbase = kk * 32 + hq * 8;
          const short8v av = *(const short8v*)&hb[rc * 256 + (kbase ^ aswz)];
          const short8v bv = *(const short8v*)&WTBs[nn * 256 + (kbase ^ bswz)];
          acc = __builtin_amdgcn_mfma_f32_16x16x32_bf16(av, bv, acc, 0, 0, 0);
        }
        if (hq < 2) {   // rows 0..7 are real
#pragma unroll
          for (int j = 0; j < 4; ++j) {
            const int prow = hq * 4 + j;
            psh[prow * 80 + nn] = acc[j] + biasL[nn];
          }
        }
      }
    }
    __syncthreads();
    // ---- Phase C: wave-parallel sampling; lane = (r, head, k) ----
    if (tid < 256) {
      const int g8 = tid >> 3, k = tid & 7;
      const int r = g8 >> 2, head = g8 & 3;
      const int row = row0 + r;
      const int base = head ? (30 + 15 * (head - 1)) : 0;
      const uint32_t g0 = keysL[t * 16 + head * 4 + 0], g1 = keysL[t * 16 + head * 4 + 1];
      const uint32_t n0 = keysL[t * 16 + head * 4 + 2], n1 = keysL[t * 16 + head * 4 + 3];
      const float lk = (k < 5) ? psh[r * 80 + base + k] : -INFINITY;
      float mx = fmaxf(lk, __shfl_xor(lk, 1));
      mx = fmaxf(mx, __shfl_xor(mx, 2));
      mx = fmaxf(mx, __shfl_xor(mx, 4));
      const float ek = (k < 5) ? fexp(lk - mx) : 0.0f;
      float ss = ek + __shfl_xor(ek, 1);
      ss += __shfl_xor(ss, 2);
      ss += __shfl_xor(ss, 4);
      const float rss = frcp(ss);
      // gumbel argmax, first-max-wins
      float v = -INFINITY;
      if (k < 5) {
        float uv = u01f(pbits(g0, g1, (uint32_t)(row * 5 + k)));
        uv = fmaxf(TINYF, uv * (1.0f - TINYF) + TINYF);
        v = lk - flog(-flog(uv));
      }
      float vm = fmaxf(v, __shfl_xor(v, 1));
      vm = fmaxf(vm, __shfl_xor(vm, 2));
      vm = fmaxf(vm, __shfl_xor(vm, 4));
      int cand = (v == vm) ? k : 8;
      cand = min(cand, __shfl_xor(cand, 1));
      cand = min(cand, __shfl_xor(cand, 2));
      cand = min(cand, __shfl_xor(cand, 4));
      const int idx = cand;
      const size_t ob = head
          ? ((size_t)BN * TT * 30 + (size_t)(head - 1) * BN * TT * 15 + ((size_t)row * TT + t) * 15)
          : ((size_t)row * TT + t) * 30;
      if (k < 5) {
        out[ob + k] = ek * rss;
        out[ob + 5 + k] = psh[r * 80 + base + 5 + k];
        out[ob + 10 + k] = fexp(psh[r * 80 + base + 10 + k]);
        if (head == 0) {
          out[ob + 15 + k] = psh[r * 80 + 15 + k];
          out[ob + 20 + k] = fexp(psh[r * 80 + 20 + k]);
          out[ob + 25 + k] = ftanh(psh[r * 80 + 25 + k]);
        }
      }
      if (k == 0) {
        if (head == 0) {
          float uz0 = u01f(pbits(n0, n1, (uint32_t)(row * 2 + 0))) * 2.0f - LO_N;
          float uz1 = u01f(pbits(n0, n1, (uint32_t)(row * 2 + 1))) * 2.0f - LO_N;
          uz0 = fmaxf(-LO_N, uz0); uz1 = fmaxf(-LO_N, uz1);
          const float z0 = 1.41421356f * erfinv_f(uz0);
          const float z1 = 1.41421356f * erfinv_f(uz1);
          const float mu = psh[r * 80 + 5 + idx];
          const float sl = fexp(psh[r * 80 + 10 + idx]);
          const float mula = psh[r * 80 + 15 + idx];
          const float sla = fexp(psh[r * 80 + 20 + idx]);
          const float rho = ftanh(psh[r * 80 + 25 + idx]);
          conds[r * 8 + 0] = mu + sl * z0;
          conds[r * 8 + 1] = mula + sla * (rho * z0 + sqrtf(1.0f - rho * rho) * z1);
        } else {
          float uz = u01f(pbits(n0, n1, (uint32_t)row)) * 2.0f - LO_N;
          uz = fmaxf(-LO_N, uz);
          const float zz = 1.41421356f * erfinv_f(uz);
          conds[r * 8 + 1 + head] =
              psh[r * 80 + base + 5 + idx] + fexp(psh[r * 80 + base + 10 + idx]) * zz;
        }
      }
    }
    __syncthreads();
  }
}

extern "C" void kernel_launch(void* const* d_in, const int* in_sizes, int n_in,
                              void* d_out, int out_size, void* d_ws, size_t ws_size,
                              hipStream_t stream) {
  const float* conditions = (const float*)d_in[0];
  const float* state_h = (const float*)d_in[1];
  const float* state_c = (const float*)d_in[2];
  // d_in[3] = steps_n (=20, compile-time TT)
  const float* We1 = (const float*)d_in[4];
  const float* be1 = (const float*)d_in[5];
  const float* We2 = (const float*)d_in[6];
  const float* be2 = (const float*)d_in[7];
  const float* Wk  = (const float*)d_in[8];
  const float* Wr  = (const float*)d_in[9];
  const float* bl  = (const float*)d_in[10];
  const float* Wm  = (const float*)d_in[11];
  const float* bm  = (const float*)d_in[12];
  const float* Wy  = (const float*)d_in[13];
  const float* by  = (const float*)d_in[14];
  const float* Wf  = (const float*)d_in[15];
  const float* bf  = (const float*)d_in[16];
  const float* Wfa = (const float*)d_in[17];
  const float* bfa = (const float*)d_in[18];
  float* ws = (float*)d_ws;   // needs WS_END*4 ~= 1.24 MB
  float* out = (float*)d_out;

  prep_a<<<dim3(1111), dim3(256), 0, stream>>>(
      Wk, Wr, We1, be1, We2, be2, Wm, bm, Wy, by, Wf, bf, Wfa, bfa, ws);
  prep_b<<<dim3(4), dim3(256), 0, stream>>>(Wk, bl, ws);
  decode_main<<<dim3(BN / 8), dim3(512), 0, stream>>>(
      conditions, state_h, state_c, ws, out);
}